// Round 1
// baseline (4358.694 us; speedup 1.0000x reference)
//
#include <hip/hip_runtime.h>
#include <hip/hip_bf16.h>
#include <stdint.h>

#define Bb 8
#define Ss 1024
#define Ee 512
#define Hh 8
#define Dh 64
#define FFNd 2048
#define EPSv 1e-5f

typedef float f32x4 __attribute__((ext_vector_type(4)));
typedef int   i32x4 __attribute__((ext_vector_type(4)));

__device__ inline float bf2f(ushort u) {
    uint32_t x = ((uint32_t)u) << 16; float f; __builtin_memcpy(&f, &x, 4); return f;
}
__device__ inline ushort f2bf(float f) {
    uint32_t x; __builtin_memcpy(&x, &f, 4);
    uint32_t r = (x + 0x7FFFu + ((x >> 16) & 1u)) >> 16; return (ushort)r;
}

// ---------------- fp32 -> bf16 conversion ----------------
__global__ void cvt_f32_bf16(const float* __restrict__ in, ushort* __restrict__ out, int n4) {
    int i = blockIdx.x * blockDim.x + threadIdx.x;
    if (i < n4) {
        float4 v = ((const float4*)in)[i];
        ushort4 o;
        o.x = f2bf(v.x); o.y = f2bf(v.y); o.z = f2bf(v.z); o.w = f2bf(v.w);
        ((ushort4*)out)[i] = o;
    }
}

// ---------------- bf16 GEMM: C[M,N] = A[M,K] @ B[N,K]^T + bias (+relu) ----------------
// 128x128 tile, BK=32, 256 threads (4 waves), each wave owns a 64x64 quadrant.
template<bool OUT_BF16, bool RELU>
__global__ __launch_bounds__(256) void gemm_bt(const ushort* __restrict__ A,
                                               const ushort* __restrict__ Bm,
                                               const float* __restrict__ bias,
                                               void* __restrict__ C,
                                               int M, int N, int K) {
    __shared__ ushort Alds[128 * 32];
    __shared__ ushort Blds[128 * 32];
    int tid  = threadIdx.x;
    int lane = tid & 63, w = tid >> 6;
    int wr = w >> 1, wc = w & 1;
    int g  = lane >> 4, fr = lane & 15;
    int m0 = blockIdx.y * 128, n0 = blockIdx.x * 128;

    int lr = tid >> 2;            // staging row 0..63
    int ko = (tid & 3) * 8;       // staging k-offset (elems)
    const ushort* pa0 = A  + (size_t)(m0 + lr) * K + ko;
    const ushort* pa1 = pa0 + (size_t)64 * K;
    const ushort* pb0 = Bm + (size_t)(n0 + lr) * K + ko;
    const ushort* pb1 = pb0 + (size_t)64 * K;
    ushort* la0 = Alds + lr * 32 + ko;
    ushort* la1 = la0 + 64 * 32;
    ushort* lb0 = Blds + lr * 32 + ko;
    ushort* lb1 = lb0 + 64 * 32;

    f32x4 acc[4][4] = {};

    for (int kb = 0; kb < K; kb += 32) {
        i32x4 va0 = *(const i32x4*)(pa0 + kb);
        i32x4 va1 = *(const i32x4*)(pa1 + kb);
        i32x4 vb0 = *(const i32x4*)(pb0 + kb);
        i32x4 vb1 = *(const i32x4*)(pb1 + kb);
        __syncthreads();
        *(i32x4*)la0 = va0; *(i32x4*)la1 = va1;
        *(i32x4*)lb0 = vb0; *(i32x4*)lb1 = vb1;
        __syncthreads();
        i32x4 af[4], bfr[4];
        #pragma unroll
        for (int mt = 0; mt < 4; ++mt)
            af[mt] = *(const i32x4*)(Alds + (wr * 64 + mt * 16 + fr) * 32 + g * 8);
        #pragma unroll
        for (int nt = 0; nt < 4; ++nt)
            bfr[nt] = *(const i32x4*)(Blds + (wc * 64 + nt * 16 + fr) * 32 + g * 8);
        #pragma unroll
        for (int mt = 0; mt < 4; ++mt)
            #pragma unroll
            for (int nt = 0; nt < 4; ++nt)
                asm("v_mfma_f32_16x16x32_bf16 %0, %1, %2, %0"
                    : "+v"(acc[mt][nt]) : "v"(af[mt]), "v"(bfr[nt]));
    }

    #pragma unroll
    for (int mt = 0; mt < 4; ++mt) {
        int r0 = m0 + wr * 64 + mt * 16 + g * 4;
        #pragma unroll
        for (int nt = 0; nt < 4; ++nt) {
            int c = n0 + wc * 64 + nt * 16 + fr;
            float bv = bias[c];
            #pragma unroll
            for (int r = 0; r < 4; ++r) {
                float v = acc[mt][nt][r] + bv;
                if (RELU) v = v > 0.f ? v : 0.f;
                if (OUT_BF16) ((ushort*)C)[(size_t)(r0 + r) * N + c] = f2bf(v);
                else          ((float*)C)[(size_t)(r0 + r) * N + c] = v;
            }
        }
    }
}

// ---------------- local windowed attention: one wave per query ----------------
__global__ __launch_bounds__(256) void attn_local(const ushort* __restrict__ qkv,
                                                  ushort* __restrict__ out) {
    int wid  = blockIdx.x * 4 + (threadIdx.x >> 6);
    int lane = threadIdx.x & 63;
    int q  = wid & (Ss - 1);
    int bh = wid >> 10;
    int h  = bh & (Hh - 1), b = bh >> 3;
    const ushort* base = qkv + (size_t)b * Ss * (3 * Ee) + h * Dh + lane;
    float qv = bf2f(base[(size_t)q * (3 * Ee)]) * 0.125f;
    float l = 0.f, acc = 0.f;
    int t0 = q - 5 < 0 ? 0 : q - 5;
    int t1 = q + 5 > Ss - 1 ? Ss - 1 : q + 5;
    for (int t = t0; t <= t1; ++t) {
        float kv = bf2f(base[(size_t)t * (3 * Ee) + Ee]);
        float p = qv * kv;
        #pragma unroll
        for (int off = 32; off; off >>= 1) p += __shfl_xor(p, off);
        float e = __expf(p);
        l += e;
        acc += e * bf2f(base[(size_t)t * (3 * Ee) + 2 * Ee]);
    }
    out[(size_t)(b * Ss + q) * Ee + h * Dh + lane] = f2bf(acc / l);
}

// ---------------- global attention: one wave per query, online accumulation ----------------
__global__ __launch_bounds__(256) void attn_global(const ushort* __restrict__ qkv,
                                                   ushort* __restrict__ out) {
    int wid  = blockIdx.x * 4 + (threadIdx.x >> 6);
    int lane = threadIdx.x & 63;
    int q  = wid & (Ss - 1);
    int bh = wid >> 10;
    int h  = bh & (Hh - 1), b = bh >> 3;
    const ushort* base = qkv + (size_t)b * Ss * (3 * Ee) + h * Dh + lane;
    float qv = bf2f(base[(size_t)q * (3 * Ee)]) * 0.125f;
    float l = 0.f, acc = 0.f;
    const ushort* kp = base + Ee;
    const ushort* vp = base + 2 * Ee;
    #pragma unroll 4
    for (int t = 0; t < Ss; ++t) {
        float kv = bf2f(kp[(size_t)t * (3 * Ee)]);
        float p = qv * kv;
        #pragma unroll
        for (int off = 32; off; off >>= 1) p += __shfl_xor(p, off);
        float e = __expf(p);   // scores bounded (~|p|<3): safe without max-subtract
        l += e;
        acc += e * bf2f(vp[(size_t)t * (3 * Ee)]);
    }
    out[(size_t)(b * Ss + q) * Ee + h * Dh + lane] = f2bf(acc / l);
}

// ---------------- fused residual(3-way) + LayerNorm, dual write (bf16 + f32) ----------------
__global__ __launch_bounds__(256) void ln_add3(const float* __restrict__ x,
                                               const float* __restrict__ p1,
                                               const float* __restrict__ p2,
                                               const float* __restrict__ gam,
                                               const float* __restrict__ bet,
                                               ushort* __restrict__ yb,
                                               float* __restrict__ yf) {
    int row  = blockIdx.x * 4 + (threadIdx.x >> 6);
    int lane = threadIdx.x & 63;
    size_t off = (size_t)row * Ee + lane * 8;
    float hv[8];
    float4 a0 = *(const float4*)(x + off),  a1 = *(const float4*)(x + off + 4);
    float4 b0 = *(const float4*)(p1 + off), b1 = *(const float4*)(p1 + off + 4);
    float4 c0 = *(const float4*)(p2 + off), c1 = *(const float4*)(p2 + off + 4);
    hv[0] = a0.x + b0.x + c0.x; hv[1] = a0.y + b0.y + c0.y;
    hv[2] = a0.z + b0.z + c0.z; hv[3] = a0.w + b0.w + c0.w;
    hv[4] = a1.x + b1.x + c1.x; hv[5] = a1.y + b1.y + c1.y;
    hv[6] = a1.z + b1.z + c1.z; hv[7] = a1.w + b1.w + c1.w;
    float s = 0.f;
    #pragma unroll
    for (int i = 0; i < 8; ++i) s += hv[i];
    #pragma unroll
    for (int o = 32; o; o >>= 1) s += __shfl_xor(s, o);
    float mu = s * (1.f / Ee);
    float vs = 0.f;
    #pragma unroll
    for (int i = 0; i < 8; ++i) { float d = hv[i] - mu; vs += d * d; }
    #pragma unroll
    for (int o = 32; o; o >>= 1) vs += __shfl_xor(vs, o);
    float rs = rsqrtf(vs * (1.f / Ee) + EPSv);
    #pragma unroll
    for (int i = 0; i < 8; ++i) {
        float yv = (hv[i] - mu) * rs * gam[lane * 8 + i] + bet[lane * 8 + i];
        yf[off + i] = yv;
        yb[off + i] = f2bf(yv);
    }
}

// ---------------- fused residual(2-way) + LayerNorm -> f32 out ----------------
__global__ __launch_bounds__(256) void ln_add2(const float* __restrict__ a,
                                               const float* __restrict__ bsrc,
                                               const float* __restrict__ gam,
                                               const float* __restrict__ bet,
                                               float* __restrict__ outp) {
    int row  = blockIdx.x * 4 + (threadIdx.x >> 6);
    int lane = threadIdx.x & 63;
    size_t off = (size_t)row * Ee + lane * 8;
    float hv[8];
    float4 a0 = *(const float4*)(a + off),    a1 = *(const float4*)(a + off + 4);
    float4 b0 = *(const float4*)(bsrc + off), b1 = *(const float4*)(bsrc + off + 4);
    hv[0] = a0.x + b0.x; hv[1] = a0.y + b0.y; hv[2] = a0.z + b0.z; hv[3] = a0.w + b0.w;
    hv[4] = a1.x + b1.x; hv[5] = a1.y + b1.y; hv[6] = a1.z + b1.z; hv[7] = a1.w + b1.w;
    float s = 0.f;
    #pragma unroll
    for (int i = 0; i < 8; ++i) s += hv[i];
    #pragma unroll
    for (int o = 32; o; o >>= 1) s += __shfl_xor(s, o);
    float mu = s * (1.f / Ee);
    float vs = 0.f;
    #pragma unroll
    for (int i = 0; i < 8; ++i) { float d = hv[i] - mu; vs += d * d; }
    #pragma unroll
    for (int o = 32; o; o >>= 1) vs += __shfl_xor(vs, o);
    float rs = rsqrtf(vs * (1.f / Ee) + EPSv);
    #pragma unroll
    for (int i = 0; i < 8; ++i)
        outp[off + i] = (hv[i] - mu) * rs * gam[lane * 8 + i] + bet[lane * 8 + i];
}

extern "C" void kernel_launch(void* const* d_in, const int* in_sizes, int n_in,
                              void* d_out, int out_size, void* d_ws, size_t ws_size,
                              hipStream_t stream) {
    const float* x      = (const float*)d_in[0];
    const float* l_in_w = (const float*)d_in[1];
    const float* l_in_b = (const float*)d_in[2];
    const float* l_out_w= (const float*)d_in[3];
    const float* l_out_b= (const float*)d_in[4];
    const float* g_in_w = (const float*)d_in[5];
    const float* g_in_b = (const float*)d_in[6];
    const float* g_out_w= (const float*)d_in[7];
    const float* g_out_b= (const float*)d_in[8];
    const float* ffn_w1 = (const float*)d_in[9];
    const float* ffn_b1 = (const float*)d_in[10];
    const float* ffn_w2 = (const float*)d_in[11];
    const float* ffn_b2 = (const float*)d_in[12];
    const float* ln1_g  = (const float*)d_in[13];
    const float* ln1_b  = (const float*)d_in[14];
    const float* ln2_g  = (const float*)d_in[15];
    const float* ln2_b  = (const float*)d_in[16];

    char* ws = (char*)d_ws;
    // ---- workspace layout (peak 92.3 MB, liveness-checked) ----
    ushort* xb       = (ushort*)(ws + 0);          // 8.39 MB
    ushort* wb       = (ushort*)(ws + 8388608);    // 8.39 MB of bf16 weights
    ushort* l_in_wb  = wb;
    ushort* g_in_wb  = wb + 786432;
    ushort* l_out_wb = wb + 1572864;
    ushort* g_out_wb = wb + 1835008;
    ushort* w1b      = wb + 2097152;
    ushort* w2b      = wb + 3145728;
    ushort* qkvLb    = (ushort*)(ws + 16777216);   // 25.2 MB
    ushort* qkvGb    = (ushort*)(ws + 41943040);   // 25.2 MB
    ushort* attnLb   = (ushort*)(ws + 67108864);   // 8.39 MB
    ushort* attnGb   = (ushort*)(ws + 75497472);   // 8.39 MB
    float*  projL    = (float*)(ws + 16777216);    // reuse qkvL (dead after attn_local)
    float*  projG    = (float*)(ws + 33554432);    // reuse qkvL tail + qkvG head (dead)
    ushort* y1b      = (ushort*)(ws + 50331648);   // reuse qkvG mid (dead)
    float*  y1f      = (float*)(ws + 58720256);    // reuse qkvG tail + attnL (dead)
    ushort* ffn1b    = (ushort*)(ws + 16777216);   // reuse projL/projG (dead after ln1)
    float*  ffn2f    = (float*)(ws + 75497472);    // reuse attnG (dead) + fresh tail

    const int M = Bb * Ss;   // 8192

    auto cvt = [&](const float* in, ushort* out, int n) {
        int n4 = n / 4;
        cvt_f32_bf16<<<dim3((n4 + 255) / 256), dim3(256), 0, stream>>>(in, out, n4);
    };
    cvt(x,       xb,       Bb * Ss * Ee);
    cvt(l_in_w,  l_in_wb,  3 * Ee * Ee);
    cvt(g_in_w,  g_in_wb,  3 * Ee * Ee);
    cvt(l_out_w, l_out_wb, Ee * Ee);
    cvt(g_out_w, g_out_wb, Ee * Ee);
    cvt(ffn_w1,  w1b,      FFNd * Ee);
    cvt(ffn_w2,  w2b,      Ee * FFNd);

    // QKV projections (bf16 out)
    gemm_bt<true, false><<<dim3((3 * Ee) / 128, M / 128), 256, 0, stream>>>(
        xb, l_in_wb, l_in_b, qkvLb, M, 3 * Ee, Ee);
    gemm_bt<true, false><<<dim3((3 * Ee) / 128, M / 128), 256, 0, stream>>>(
        xb, g_in_wb, g_in_b, qkvGb, M, 3 * Ee, Ee);

    // attention
    attn_local<<<dim3(Bb * Hh * Ss / 4), 256, 0, stream>>>(qkvLb, attnLb);
    attn_global<<<dim3(Bb * Hh * Ss / 4), 256, 0, stream>>>(qkvGb, attnGb);

    // output projections (f32 out)
    gemm_bt<false, false><<<dim3(Ee / 128, M / 128), 256, 0, stream>>>(
        attnLb, l_out_wb, l_out_b, projL, M, Ee, Ee);
    gemm_bt<false, false><<<dim3(Ee / 128, M / 128), 256, 0, stream>>>(
        attnGb, g_out_wb, g_out_b, projG, M, Ee, Ee);

    // residual + LN1 (writes bf16 for FFN, f32 for residual-2)
    ln_add3<<<dim3(M / 4), 256, 0, stream>>>(x, projL, projG, ln1_g, ln1_b, y1b, y1f);

    // FFN
    gemm_bt<true, true><<<dim3(FFNd / 128, M / 128), 256, 0, stream>>>(
        y1b, w1b, ffn_b1, ffn1b, M, FFNd, Ee);
    gemm_bt<false, false><<<dim3(Ee / 128, M / 128), 256, 0, stream>>>(
        ffn1b, w2b, ffn_b2, ffn2f, M, Ee, FFNd);

    // residual + LN2 -> output
    ln_add2<<<dim3(M / 4), 256, 0, stream>>>(y1f, ffn2f, ln2_g, ln2_b, (float*)d_out);
}

// Round 2
// 374.571 us; speedup vs baseline: 11.6365x; 11.6365x over previous
//
#include <hip/hip_runtime.h>
#include <hip/hip_bf16.h>
#include <stdint.h>

#define Bb 8
#define Ss 1024
#define Ee 512
#define Hh 8
#define Dh 64
#define FFNd 2048
#define EPSv 1e-5f

typedef float f32x4 __attribute__((ext_vector_type(4)));
typedef int   i32x4 __attribute__((ext_vector_type(4)));

__device__ inline float bf2f(ushort u) {
    uint32_t x = ((uint32_t)u) << 16; float f; __builtin_memcpy(&f, &x, 4); return f;
}
__device__ inline ushort f2bf(float f) {
    uint32_t x; __builtin_memcpy(&x, &f, 4);
    uint32_t r = (x + 0x7FFFu + ((x >> 16) & 1u)) >> 16; return (ushort)r;
}

// ---------------- fp32 -> bf16 conversion ----------------
__global__ void cvt_f32_bf16(const float* __restrict__ in, ushort* __restrict__ out, int n4) {
    int i = blockIdx.x * blockDim.x + threadIdx.x;
    if (i < n4) {
        float4 v = ((const float4*)in)[i];
        ushort4 o;
        o.x = f2bf(v.x); o.y = f2bf(v.y); o.z = f2bf(v.z); o.w = f2bf(v.w);
        ((ushort4*)out)[i] = o;
    }
}

// ---------------- bf16 GEMM: C[M,N] = A[M,K] @ B[N,K]^T + bias (+relu) ----------------
template<bool OUT_BF16, bool RELU>
__global__ __launch_bounds__(256) void gemm_bt(const ushort* __restrict__ A,
                                               const ushort* __restrict__ Bm,
                                               const float* __restrict__ bias,
                                               void* __restrict__ C,
                                               int M, int N, int K) {
    __shared__ ushort Alds[128 * 32];
    __shared__ ushort Blds[128 * 32];
    int tid  = threadIdx.x;
    int lane = tid & 63, w = tid >> 6;
    int wr = w >> 1, wc = w & 1;
    int g  = lane >> 4, fr = lane & 15;
    int m0 = blockIdx.y * 128, n0 = blockIdx.x * 128;

    int lr = tid >> 2;            // staging row 0..63
    int ko = (tid & 3) * 8;       // staging k-offset (elems)
    const ushort* pa0 = A  + (size_t)(m0 + lr) * K + ko;
    const ushort* pa1 = pa0 + (size_t)64 * K;
    const ushort* pb0 = Bm + (size_t)(n0 + lr) * K + ko;
    const ushort* pb1 = pb0 + (size_t)64 * K;
    ushort* la0 = Alds + lr * 32 + ko;
    ushort* la1 = la0 + 64 * 32;
    ushort* lb0 = Blds + lr * 32 + ko;
    ushort* lb1 = lb0 + 64 * 32;

    f32x4 acc[4][4] = {};

    for (int kb = 0; kb < K; kb += 32) {
        i32x4 va0 = *(const i32x4*)(pa0 + kb);
        i32x4 va1 = *(const i32x4*)(pa1 + kb);
        i32x4 vb0 = *(const i32x4*)(pb0 + kb);
        i32x4 vb1 = *(const i32x4*)(pb1 + kb);
        __syncthreads();
        *(i32x4*)la0 = va0; *(i32x4*)la1 = va1;
        *(i32x4*)lb0 = vb0; *(i32x4*)lb1 = vb1;
        __syncthreads();
        i32x4 af[4], bfr[4];
        #pragma unroll
        for (int mt = 0; mt < 4; ++mt)
            af[mt] = *(const i32x4*)(Alds + (wr * 64 + mt * 16 + fr) * 32 + g * 8);
        #pragma unroll
        for (int nt = 0; nt < 4; ++nt)
            bfr[nt] = *(const i32x4*)(Blds + (wc * 64 + nt * 16 + fr) * 32 + g * 8);
        #pragma unroll
        for (int mt = 0; mt < 4; ++mt)
            #pragma unroll
            for (int nt = 0; nt < 4; ++nt)
                asm("v_mfma_f32_16x16x32_bf16 %0, %1, %2, %0"
                    : "+v"(acc[mt][nt]) : "v"(af[mt]), "v"(bfr[nt]));
    }

    #pragma unroll
    for (int mt = 0; mt < 4; ++mt) {
        int r0 = m0 + wr * 64 + mt * 16 + g * 4;
        #pragma unroll
        for (int nt = 0; nt < 4; ++nt) {
            int c = n0 + wc * 64 + nt * 16 + fr;
            float bv = bias[c];
            #pragma unroll
            for (int r = 0; r < 4; ++r) {
                float v = acc[mt][nt][r] + bv;
                if (RELU) v = v > 0.f ? v : 0.f;
                if (OUT_BF16) ((ushort*)C)[(size_t)(r0 + r) * N + c] = f2bf(v);
                else          ((float*)C)[(size_t)(r0 + r) * N + c] = v;
            }
        }
    }
}

// ---------------- local windowed attention: one wave per query ----------------
__global__ __launch_bounds__(256) void attn_local(const ushort* __restrict__ qkv,
                                                  ushort* __restrict__ out) {
    int wid  = blockIdx.x * 4 + (threadIdx.x >> 6);
    int lane = threadIdx.x & 63;
    int q  = wid & (Ss - 1);
    int bh = wid >> 10;
    int h  = bh & (Hh - 1), b = bh >> 3;
    const ushort* base = qkv + (size_t)b * Ss * (3 * Ee) + h * Dh + lane;
    float qv = bf2f(base[(size_t)q * (3 * Ee)]) * 0.125f;
    float l = 0.f, acc = 0.f;
    int t0 = q - 5 < 0 ? 0 : q - 5;
    int t1 = q + 5 > Ss - 1 ? Ss - 1 : q + 5;
    for (int t = t0; t <= t1; ++t) {
        float kv = bf2f(base[(size_t)t * (3 * Ee) + Ee]);
        float p = qv * kv;
        #pragma unroll
        for (int off = 32; off; off >>= 1) p += __shfl_xor(p, off);
        float e = __expf(p);
        l += e;
        acc += e * bf2f(base[(size_t)t * (3 * Ee) + 2 * Ee]);
    }
    out[(size_t)(b * Ss + q) * Ee + h * Dh + lane] = f2bf(acc / l);
}

// ---------------- global attention: MFMA flash, 128 q-rows/block, 4 waves ----------------
// Scores bounded (~|s|<8 after *0.125): exp without max-subtract (validated round 1).
__global__ __launch_bounds__(256) void attn_global_mfma(const ushort* __restrict__ qkv,
                                                        ushort* __restrict__ out) {
    __shared__ ushort Klds[64 * 64];       // K[kv][d], XOR-swizzled
    __shared__ ushort Vtlds[64 * 64];      // V^T[d][kv], XOR-swizzled
    __shared__ ushort Plds[4][32 * 64];    // per-wave P[q][kv], XOR-swizzled
    int tid  = threadIdx.x;
    int lane = tid & 63, w = tid >> 6;
    int fr = lane & 15, g = lane >> 4;
    int qtile = blockIdx.x & 7;
    int bh = blockIdx.x >> 3;
    int h = bh & 7, b = bh >> 3;
    const size_t bbase = (size_t)b * Ss * (3 * Ee);
    const ushort* qp = qkv + bbase + h * Dh;
    const ushort* kbase = qkv + bbase + Ee + h * Dh;
    const ushort* vbase = qkv + bbase + 2 * Ee + h * Dh;

    // Q fragments in registers (A-frag: row=fr, k=g*8..+7 within 32-block)
    i32x4 qf[2][2];
    int q0 = qtile * 128 + w * 32;
    #pragma unroll
    for (int mt = 0; mt < 2; ++mt)
        #pragma unroll
        for (int kb = 0; kb < 2; ++kb)
            qf[mt][kb] = *(const i32x4*)(qp + (size_t)(q0 + mt * 16 + fr) * (3 * Ee) + kb * 32 + g * 8);

    f32x4 oacc[2][4] = {};
    f32x4 lsum[2] = {};
    ushort* Pw = Plds[w];

    for (int kt = 0; kt < 16; ++kt) {
        int kv0 = kt * 64;
        i32x4 kr[2], vr[2];
        #pragma unroll
        for (int u = 0; u < 2; ++u) {
            int c = tid + u * 256;        // chunk: row=c>>3, col8=c&7
            int row = c >> 3, col8 = c & 7;
            kr[u] = *(const i32x4*)(kbase + (size_t)(kv0 + row) * (3 * Ee) + col8 * 8);
            vr[u] = *(const i32x4*)(vbase + (size_t)(kv0 + row) * (3 * Ee) + col8 * 8);
        }
        __syncthreads();   // previous iteration's K/Vt reads complete
        #pragma unroll
        for (int u = 0; u < 2; ++u) {
            int c = tid + u * 256;
            int row = c >> 3, col8 = c & 7;
            int kidx = (row * 64 + col8 * 8) ^ ((row & 7) << 3);
            *(i32x4*)(Klds + kidx) = kr[u];
            ushort tmp[8];
            *(i32x4*)tmp = vr[u];
            #pragma unroll
            for (int j = 0; j < 8; ++j) {
                int d = col8 * 8 + j;
                Vtlds[(d * 64 + row) ^ ((d & 7) << 3)] = tmp[j];
            }
        }
        __syncthreads();   // staging visible

        // ---- QK^T: S[32q][64kv] ----
        f32x4 sacc[2][4] = {};
        i32x4 kf[4][2];
        #pragma unroll
        for (int nt = 0; nt < 4; ++nt) {
            int kvl = nt * 16 + fr;
            #pragma unroll
            for (int kb = 0; kb < 2; ++kb)
                kf[nt][kb] = *(const i32x4*)(Klds + ((kvl * 64 + kb * 32 + g * 8) ^ ((kvl & 7) << 3)));
        }
        #pragma unroll
        for (int mt = 0; mt < 2; ++mt)
            #pragma unroll
            for (int nt = 0; nt < 4; ++nt)
                #pragma unroll
                for (int kb = 0; kb < 2; ++kb)
                    asm("v_mfma_f32_16x16x32_bf16 %0, %1, %2, %0"
                        : "+v"(sacc[mt][nt]) : "v"(qf[mt][kb]), "v"(kf[nt][kb]));

        // ---- exp + P -> LDS (C/D layout: col=fr, row=g*4+r) ----
        #pragma unroll
        for (int mt = 0; mt < 2; ++mt) {
            #pragma unroll
            for (int r = 0; r < 4; ++r) {
                int ql = mt * 16 + g * 4 + r;
                int sw = (ql & 7) << 3;
                float e0 = __expf(sacc[mt][0][r] * 0.125f);
                float e1 = __expf(sacc[mt][1][r] * 0.125f);
                float e2 = __expf(sacc[mt][2][r] * 0.125f);
                float e3 = __expf(sacc[mt][3][r] * 0.125f);
                Pw[(ql * 64 +  0 + fr) ^ sw] = f2bf(e0);
                Pw[(ql * 64 + 16 + fr) ^ sw] = f2bf(e1);
                Pw[(ql * 64 + 32 + fr) ^ sw] = f2bf(e2);
                Pw[(ql * 64 + 48 + fr) ^ sw] = f2bf(e3);
                lsum[mt][r] += (e0 + e1) + (e2 + e3);
            }
        }

        // ---- PV: O += P[32q][64kv] @ V[64kv][64d] ----
        i32x4 pa[2][2], vf[4][2];
        #pragma unroll
        for (int mt = 0; mt < 2; ++mt) {
            int ql = mt * 16 + fr;
            #pragma unroll
            for (int kb = 0; kb < 2; ++kb)
                pa[mt][kb] = *(const i32x4*)(Pw + ((ql * 64 + kb * 32 + g * 8) ^ ((ql & 7) << 3)));
        }
        #pragma unroll
        for (int dn = 0; dn < 4; ++dn) {
            int d = dn * 16 + fr;
            #pragma unroll
            for (int kb = 0; kb < 2; ++kb)
                vf[dn][kb] = *(const i32x4*)(Vtlds + ((d * 64 + kb * 32 + g * 8) ^ ((d & 7) << 3)));
        }
        #pragma unroll
        for (int mt = 0; mt < 2; ++mt)
            #pragma unroll
            for (int dn = 0; dn < 4; ++dn)
                #pragma unroll
                for (int kb = 0; kb < 2; ++kb)
                    asm("v_mfma_f32_16x16x32_bf16 %0, %1, %2, %0"
                        : "+v"(oacc[mt][dn]) : "v"(pa[mt][kb]), "v"(vf[dn][kb]));
    }

    // reduce row-sums across the 16 fr lanes (stays within g-group)
    #pragma unroll
    for (int mt = 0; mt < 2; ++mt)
        #pragma unroll
        for (int r = 0; r < 4; ++r) {
            float s = lsum[mt][r];
            s += __shfl_xor(s, 1); s += __shfl_xor(s, 2);
            s += __shfl_xor(s, 4); s += __shfl_xor(s, 8);
            lsum[mt][r] = 1.f / s;
        }

    #pragma unroll
    for (int mt = 0; mt < 2; ++mt)
        #pragma unroll
        for (int r = 0; r < 4; ++r) {
            int qg = q0 + mt * 16 + g * 4 + r;
            size_t ob = (size_t)(b * Ss + qg) * Ee + h * Dh;
            #pragma unroll
            for (int dn = 0; dn < 4; ++dn)
                out[ob + dn * 16 + fr] = f2bf(oacc[mt][dn][r] * lsum[mt][r]);
        }
}

// ---------------- fused residual(3-way) + LayerNorm, dual write (bf16 + f32) ----------------
__global__ __launch_bounds__(256) void ln_add3(const float* __restrict__ x,
                                               const float* __restrict__ p1,
                                               const float* __restrict__ p2,
                                               const float* __restrict__ gam,
                                               const float* __restrict__ bet,
                                               ushort* __restrict__ yb,
                                               float* __restrict__ yf) {
    int row  = blockIdx.x * 4 + (threadIdx.x >> 6);
    int lane = threadIdx.x & 63;
    size_t off = (size_t)row * Ee + lane * 8;
    float hv[8];
    float4 a0 = *(const float4*)(x + off),  a1 = *(const float4*)(x + off + 4);
    float4 b0 = *(const float4*)(p1 + off), b1 = *(const float4*)(p1 + off + 4);
    float4 c0 = *(const float4*)(p2 + off), c1 = *(const float4*)(p2 + off + 4);
    hv[0] = a0.x + b0.x + c0.x; hv[1] = a0.y + b0.y + c0.y;
    hv[2] = a0.z + b0.z + c0.z; hv[3] = a0.w + b0.w + c0.w;
    hv[4] = a1.x + b1.x + c1.x; hv[5] = a1.y + b1.y + c1.y;
    hv[6] = a1.z + b1.z + c1.z; hv[7] = a1.w + b1.w + c1.w;
    float s = 0.f;
    #pragma unroll
    for (int i = 0; i < 8; ++i) s += hv[i];
    #pragma unroll
    for (int o = 32; o; o >>= 1) s += __shfl_xor(s, o);
    float mu = s * (1.f / Ee);
    float vs = 0.f;
    #pragma unroll
    for (int i = 0; i < 8; ++i) { float d = hv[i] - mu; vs += d * d; }
    #pragma unroll
    for (int o = 32; o; o >>= 1) vs += __shfl_xor(vs, o);
    float rs = rsqrtf(vs * (1.f / Ee) + EPSv);
    #pragma unroll
    for (int i = 0; i < 8; ++i) {
        float yv = (hv[i] - mu) * rs * gam[lane * 8 + i] + bet[lane * 8 + i];
        yf[off + i] = yv;
        yb[off + i] = f2bf(yv);
    }
}

// ---------------- fused residual(2-way) + LayerNorm -> f32 out ----------------
__global__ __launch_bounds__(256) void ln_add2(const float* __restrict__ a,
                                               const float* __restrict__ bsrc,
                                               const float* __restrict__ gam,
                                               const float* __restrict__ bet,
                                               float* __restrict__ outp) {
    int row  = blockIdx.x * 4 + (threadIdx.x >> 6);
    int lane = threadIdx.x & 63;
    size_t off = (size_t)row * Ee + lane * 8;
    float hv[8];
    float4 a0 = *(const float4*)(a + off),    a1 = *(const float4*)(a + off + 4);
    float4 b0 = *(const float4*)(bsrc + off), b1 = *(const float4*)(bsrc + off + 4);
    hv[0] = a0.x + b0.x; hv[1] = a0.y + b0.y; hv[2] = a0.z + b0.z; hv[3] = a0.w + b0.w;
    hv[4] = a1.x + b1.x; hv[5] = a1.y + b1.y; hv[6] = a1.z + b1.z; hv[7] = a1.w + b1.w;
    float s = 0.f;
    #pragma unroll
    for (int i = 0; i < 8; ++i) s += hv[i];
    #pragma unroll
    for (int o = 32; o; o >>= 1) s += __shfl_xor(s, o);
    float mu = s * (1.f / Ee);
    float vs = 0.f;
    #pragma unroll
    for (int i = 0; i < 8; ++i) { float d = hv[i] - mu; vs += d * d; }
    #pragma unroll
    for (int o = 32; o; o >>= 1) vs += __shfl_xor(vs, o);
    float rs = rsqrtf(vs * (1.f / Ee) + EPSv);
    #pragma unroll
    for (int i = 0; i < 8; ++i)
        outp[off + i] = (hv[i] - mu) * rs * gam[lane * 8 + i] + bet[lane * 8 + i];
}

extern "C" void kernel_launch(void* const* d_in, const int* in_sizes, int n_in,
                              void* d_out, int out_size, void* d_ws, size_t ws_size,
                              hipStream_t stream) {
    const float* x      = (const float*)d_in[0];
    const float* l_in_w = (const float*)d_in[1];
    const float* l_in_b = (const float*)d_in[2];
    const float* l_out_w= (const float*)d_in[3];
    const float* l_out_b= (const float*)d_in[4];
    const float* g_in_w = (const float*)d_in[5];
    const float* g_in_b = (const float*)d_in[6];
    const float* g_out_w= (const float*)d_in[7];
    const float* g_out_b= (const float*)d_in[8];
    const float* ffn_w1 = (const float*)d_in[9];
    const float* ffn_b1 = (const float*)d_in[10];
    const float* ffn_w2 = (const float*)d_in[11];
    const float* ffn_b2 = (const float*)d_in[12];
    const float* ln1_g  = (const float*)d_in[13];
    const float* ln1_b  = (const float*)d_in[14];
    const float* ln2_g  = (const float*)d_in[15];
    const float* ln2_b  = (const float*)d_in[16];

    char* ws = (char*)d_ws;
    // ---- workspace layout (peak 92.3 MB, liveness-checked) ----
    ushort* xb       = (ushort*)(ws + 0);          // 8.39 MB
    ushort* wb       = (ushort*)(ws + 8388608);    // 8.39 MB of bf16 weights
    ushort* l_in_wb  = wb;
    ushort* g_in_wb  = wb + 786432;
    ushort* l_out_wb = wb + 1572864;
    ushort* g_out_wb = wb + 1835008;
    ushort* w1b      = wb + 2097152;
    ushort* w2b      = wb + 3145728;
    ushort* qkvLb    = (ushort*)(ws + 16777216);   // 25.2 MB
    ushort* qkvGb    = (ushort*)(ws + 41943040);   // 25.2 MB
    ushort* attnLb   = (ushort*)(ws + 67108864);   // 8.39 MB
    ushort* attnGb   = (ushort*)(ws + 75497472);   // 8.39 MB
    float*  projL    = (float*)(ws + 16777216);    // reuse qkvL (dead after attn_local)
    float*  projG    = (float*)(ws + 33554432);    // reuse qkvL tail + qkvG head (dead)
    ushort* y1b      = (ushort*)(ws + 50331648);   // reuse qkvG mid (dead)
    float*  y1f      = (float*)(ws + 58720256);    // reuse qkvG tail + attnL (dead)
    ushort* ffn1b    = (ushort*)(ws + 16777216);   // reuse projL/projG (dead after ln1)
    float*  ffn2f    = (float*)(ws + 75497472);    // reuse attnG (dead) + fresh tail

    const int M = Bb * Ss;   // 8192

    auto cvt = [&](const float* in, ushort* out, int n) {
        int n4 = n / 4;
        cvt_f32_bf16<<<dim3((n4 + 255) / 256), dim3(256), 0, stream>>>(in, out, n4);
    };
    cvt(x,       xb,       Bb * Ss * Ee);
    cvt(l_in_w,  l_in_wb,  3 * Ee * Ee);
    cvt(g_in_w,  g_in_wb,  3 * Ee * Ee);
    cvt(l_out_w, l_out_wb, Ee * Ee);
    cvt(g_out_w, g_out_wb, Ee * Ee);
    cvt(ffn_w1,  w1b,      FFNd * Ee);
    cvt(ffn_w2,  w2b,      Ee * FFNd);

    // QKV projections (bf16 out)
    gemm_bt<true, false><<<dim3((3 * Ee) / 128, M / 128), 256, 0, stream>>>(
        xb, l_in_wb, l_in_b, qkvLb, M, 3 * Ee, Ee);
    gemm_bt<true, false><<<dim3((3 * Ee) / 128, M / 128), 256, 0, stream>>>(
        xb, g_in_wb, g_in_b, qkvGb, M, 3 * Ee, Ee);

    // attention
    attn_local<<<dim3(Bb * Hh * Ss / 4), 256, 0, stream>>>(qkvLb, attnLb);
    attn_global_mfma<<<dim3(Bb * Hh * (Ss / 128)), 256, 0, stream>>>(qkvGb, attnGb);

    // output projections (f32 out)
    gemm_bt<false, false><<<dim3(Ee / 128, M / 128), 256, 0, stream>>>(
        attnLb, l_out_wb, l_out_b, projL, M, Ee, Ee);
    gemm_bt<false, false><<<dim3(Ee / 128, M / 128), 256, 0, stream>>>(
        attnGb, g_out_wb, g_out_b, projG, M, Ee, Ee);

    // residual + LN1 (writes bf16 for FFN, f32 for residual-2)
    ln_add3<<<dim3(M / 4), 256, 0, stream>>>(x, projL, projG, ln1_g, ln1_b, y1b, y1f);

    // FFN
    gemm_bt<true, true><<<dim3(FFNd / 128, M / 128), 256, 0, stream>>>(
        y1b, w1b, ffn_b1, ffn1b, M, FFNd, Ee);
    gemm_bt<false, false><<<dim3(Ee / 128, M / 128), 256, 0, stream>>>(
        ffn1b, w2b, ffn_b2, ffn2f, M, Ee, FFNd);

    // residual + LN2 -> output
    ln_add2<<<dim3(M / 4), 256, 0, stream>>>(y1f, ffn2f, ln2_g, ln2_b, (float*)d_out);
}

// Round 3
// 339.384 us; speedup vs baseline: 12.8429x; 1.1037x over previous
//
#include <hip/hip_runtime.h>
#include <hip/hip_bf16.h>
#include <stdint.h>

#define Bb 8
#define Ss 1024
#define Ee 512
#define Hh 8
#define Dh 64
#define FFNd 2048
#define EPSv 1e-5f

typedef float f32x4 __attribute__((ext_vector_type(4)));
typedef int   i32x4 __attribute__((ext_vector_type(4)));

__device__ inline float bf2f(ushort u) {
    uint32_t x = ((uint32_t)u) << 16; float f; __builtin_memcpy(&f, &x, 4); return f;
}
__device__ inline ushort f2bf(float f) {
    uint32_t x; __builtin_memcpy(&x, &f, 4);
    uint32_t r = (x + 0x7FFFu + ((x >> 16) & 1u)) >> 16; return (ushort)r;
}

// async global->LDS, 16B per lane; LDS dest = wave-uniform base + lane*16B
__device__ inline void gload16(const ushort* g, ushort* l) {
    __builtin_amdgcn_global_load_lds((const __attribute__((address_space(1))) void*)g,
                                     (__attribute__((address_space(3))) void*)l,
                                     16, 0, 0);
}

// ---------------- fp32 -> bf16 conversion ----------------
__global__ void cvt_f32_bf16(const float* __restrict__ in, ushort* __restrict__ out, int n4) {
    int i = blockIdx.x * blockDim.x + threadIdx.x;
    if (i < n4) {
        float4 v = ((const float4*)in)[i];
        ushort4 o;
        o.x = f2bf(v.x); o.y = f2bf(v.y); o.z = f2bf(v.z); o.w = f2bf(v.w);
        ((ushort4*)out)[i] = o;
    }
}

// ---------------- bf16 GEMM: C[M,N] = A[M,K] @ B[N,K]^T + bias (+relu) ----------------
// 128x128 tile, BK=32, 256 threads (4 waves), global_load_lds width-16 staging (m97 structure).
template<bool OUT_BF16, bool RELU>
__global__ __launch_bounds__(256) void gemm_bt(const ushort* __restrict__ A,
                                               const ushort* __restrict__ Bm,
                                               const float* __restrict__ bias,
                                               void* __restrict__ C,
                                               int M, int N, int K) {
    __shared__ ushort Alds[128 * 32];
    __shared__ ushort Blds[128 * 32];
    int tid  = threadIdx.x;
    int lane = tid & 63, w = tid >> 6;
    int wr = w >> 1, wc = w & 1;
    int g  = lane >> 4, fr = lane & 15;
    int m0 = blockIdx.y * 128, n0 = blockIdx.x * 128;

    // staging: wave w owns 16-row chunks c=2w and c=2w+1; lane i -> row c*16+(i>>2), col (i&3)*8
    int lr4 = lane >> 2;
    int lc8 = (lane & 3) * 8;
    const ushort* gA0 = A  + (size_t)(m0 + (w * 2) * 16 + lr4) * K + lc8;
    const ushort* gA1 = gA0 + (size_t)16 * K;
    const ushort* gB0 = Bm + (size_t)(n0 + (w * 2) * 16 + lr4) * K + lc8;
    const ushort* gB1 = gB0 + (size_t)16 * K;
    ushort* lA0 = Alds + (w * 2) * 16 * 32;   // wave-uniform; HW adds lane*16B
    ushort* lA1 = lA0 + 16 * 32;
    ushort* lB0 = Blds + (w * 2) * 16 * 32;
    ushort* lB1 = lB0 + 16 * 32;

    f32x4 acc[4][4] = {};

    for (int kb = 0; kb < K; kb += 32) {
        __syncthreads();                    // prev iteration's LDS reads done
        gload16(gA0 + kb, lA0);
        gload16(gA1 + kb, lA1);
        gload16(gB0 + kb, lB0);
        gload16(gB1 + kb, lB1);
        __syncthreads();                    // compiler drains vmcnt before barrier
        i32x4 af[4], bfr[4];
        #pragma unroll
        for (int mt = 0; mt < 4; ++mt)
            af[mt] = *(const i32x4*)(Alds + (wr * 64 + mt * 16 + fr) * 32 + g * 8);
        #pragma unroll
        for (int nt = 0; nt < 4; ++nt)
            bfr[nt] = *(const i32x4*)(Blds + (wc * 64 + nt * 16 + fr) * 32 + g * 8);
        #pragma unroll
        for (int mt = 0; mt < 4; ++mt)
            #pragma unroll
            for (int nt = 0; nt < 4; ++nt)
                asm("v_mfma_f32_16x16x32_bf16 %0, %1, %2, %0"
                    : "+v"(acc[mt][nt]) : "v"(af[mt]), "v"(bfr[nt]));
    }

    #pragma unroll
    for (int mt = 0; mt < 4; ++mt) {
        int r0 = m0 + wr * 64 + mt * 16 + g * 4;
        #pragma unroll
        for (int nt = 0; nt < 4; ++nt) {
            int c = n0 + wc * 64 + nt * 16 + fr;
            float bv = bias[c];
            #pragma unroll
            for (int r = 0; r < 4; ++r) {
                float v = acc[mt][nt][r] + bv;
                if (RELU) v = v > 0.f ? v : 0.f;
                if (OUT_BF16) ((ushort*)C)[(size_t)(r0 + r) * N + c] = f2bf(v);
                else          ((float*)C)[(size_t)(r0 + r) * N + c] = v;
            }
        }
    }
}

// ---------------- local windowed attention: MFMA flash over the 4 band tiles ----------------
__global__ __launch_bounds__(256) void attn_local_mfma(const ushort* __restrict__ qkv,
                                                       ushort* __restrict__ out) {
    __shared__ ushort Klds[64 * 64];
    __shared__ ushort Vtlds[64 * 64];
    __shared__ ushort Plds[4][32 * 64];
    int tid  = threadIdx.x;
    int lane = tid & 63, w = tid >> 6;
    int fr = lane & 15, g = lane >> 4;
    int qtile = blockIdx.x & 7;
    int bh = blockIdx.x >> 3;
    int h = bh & 7, b = bh >> 3;
    const size_t bbase = (size_t)b * Ss * (3 * Ee);
    const ushort* qp = qkv + bbase + h * Dh;
    const ushort* kbase = qkv + bbase + Ee + h * Dh;
    const ushort* vbase = qkv + bbase + 2 * Ee + h * Dh;

    i32x4 qf[2][2];
    int q0 = qtile * 128 + w * 32;
    #pragma unroll
    for (int mt = 0; mt < 2; ++mt)
        #pragma unroll
        for (int kb = 0; kb < 2; ++kb)
            qf[mt][kb] = *(const i32x4*)(qp + (size_t)(q0 + mt * 16 + fr) * (3 * Ee) + kb * 32 + g * 8);

    f32x4 oacc[2][4] = {};
    f32x4 lsum[2] = {};
    ushort* Pw = Plds[w];

    int tq2 = qtile * 2;
    int kt0 = tq2 > 0 ? tq2 - 1 : 0;
    int kt1 = tq2 + 2 < 16 ? tq2 + 2 : 15;
    for (int kt = kt0; kt <= kt1; ++kt) {
        int kv0 = kt * 64;
        i32x4 kr[2], vr[2];
        #pragma unroll
        for (int u = 0; u < 2; ++u) {
            int c = tid + u * 256;
            int row = c >> 3, col8 = c & 7;
            kr[u] = *(const i32x4*)(kbase + (size_t)(kv0 + row) * (3 * Ee) + col8 * 8);
            vr[u] = *(const i32x4*)(vbase + (size_t)(kv0 + row) * (3 * Ee) + col8 * 8);
        }
        __syncthreads();
        #pragma unroll
        for (int u = 0; u < 2; ++u) {
            int c = tid + u * 256;
            int row = c >> 3, col8 = c & 7;
            int kidx = (row * 64 + col8 * 8) ^ ((row & 7) << 3);
            *(i32x4*)(Klds + kidx) = kr[u];
            ushort tmp[8];
            *(i32x4*)tmp = vr[u];
            #pragma unroll
            for (int j = 0; j < 8; ++j) {
                int d = col8 * 8 + j;
                Vtlds[(d * 64 + row) ^ ((d & 7) << 3)] = tmp[j];
            }
        }
        __syncthreads();

        // wave active iff its query band overlaps this kv tile
        bool active = (kv0 <= q0 + 36) && (kv0 + 63 >= q0 - 5);
        if (active) {
            f32x4 sacc[2][4] = {};
            i32x4 kf[4][2];
            #pragma unroll
            for (int nt = 0; nt < 4; ++nt) {
                int kvl = nt * 16 + fr;
                #pragma unroll
                for (int kb = 0; kb < 2; ++kb)
                    kf[nt][kb] = *(const i32x4*)(Klds + ((kvl * 64 + kb * 32 + g * 8) ^ ((kvl & 7) << 3)));
            }
            #pragma unroll
            for (int mt = 0; mt < 2; ++mt)
                #pragma unroll
                for (int nt = 0; nt < 4; ++nt)
                    #pragma unroll
                    for (int kb = 0; kb < 2; ++kb)
                        asm("v_mfma_f32_16x16x32_bf16 %0, %1, %2, %0"
                            : "+v"(sacc[mt][nt]) : "v"(qf[mt][kb]), "v"(kf[nt][kb]));

            // masked exp + P -> LDS
            #pragma unroll
            for (int mt = 0; mt < 2; ++mt) {
                #pragma unroll
                for (int r = 0; r < 4; ++r) {
                    int ql = mt * 16 + g * 4 + r;
                    int sw = (ql & 7) << 3;
                    int d0 = (q0 + ql) - (kv0 + fr);
                    int d1 = d0 - 16, d2 = d0 - 32, d3 = d0 - 48;
                    float e0 = (d0 >= -5 && d0 <= 5) ? __expf(sacc[mt][0][r] * 0.125f) : 0.f;
                    float e1 = (d1 >= -5 && d1 <= 5) ? __expf(sacc[mt][1][r] * 0.125f) : 0.f;
                    float e2 = (d2 >= -5 && d2 <= 5) ? __expf(sacc[mt][2][r] * 0.125f) : 0.f;
                    float e3 = (d3 >= -5 && d3 <= 5) ? __expf(sacc[mt][3][r] * 0.125f) : 0.f;
                    Pw[(ql * 64 +  0 + fr) ^ sw] = f2bf(e0);
                    Pw[(ql * 64 + 16 + fr) ^ sw] = f2bf(e1);
                    Pw[(ql * 64 + 32 + fr) ^ sw] = f2bf(e2);
                    Pw[(ql * 64 + 48 + fr) ^ sw] = f2bf(e3);
                    lsum[mt][r] += (e0 + e1) + (e2 + e3);
                }
            }

            i32x4 pa[2][2], vf[4][2];
            #pragma unroll
            for (int mt = 0; mt < 2; ++mt) {
                int ql = mt * 16 + fr;
                #pragma unroll
                for (int kb = 0; kb < 2; ++kb)
                    pa[mt][kb] = *(const i32x4*)(Pw + ((ql * 64 + kb * 32 + g * 8) ^ ((ql & 7) << 3)));
            }
            #pragma unroll
            for (int dn = 0; dn < 4; ++dn) {
                int d = dn * 16 + fr;
                #pragma unroll
                for (int kb = 0; kb < 2; ++kb)
                    vf[dn][kb] = *(const i32x4*)(Vtlds + ((d * 64 + kb * 32 + g * 8) ^ ((d & 7) << 3)));
            }
            #pragma unroll
            for (int mt = 0; mt < 2; ++mt)
                #pragma unroll
                for (int dn = 0; dn < 4; ++dn)
                    #pragma unroll
                    for (int kb = 0; kb < 2; ++kb)
                        asm("v_mfma_f32_16x16x32_bf16 %0, %1, %2, %0"
                            : "+v"(oacc[mt][dn]) : "v"(pa[mt][kb]), "v"(vf[dn][kb]));
        }
    }

    #pragma unroll
    for (int mt = 0; mt < 2; ++mt)
        #pragma unroll
        for (int r = 0; r < 4; ++r) {
            float s = lsum[mt][r];
            s += __shfl_xor(s, 1); s += __shfl_xor(s, 2);
            s += __shfl_xor(s, 4); s += __shfl_xor(s, 8);
            lsum[mt][r] = 1.f / s;
        }

    #pragma unroll
    for (int mt = 0; mt < 2; ++mt)
        #pragma unroll
        for (int r = 0; r < 4; ++r) {
            int qg = q0 + mt * 16 + g * 4 + r;
            size_t ob = (size_t)(b * Ss + qg) * Ee + h * Dh;
            #pragma unroll
            for (int dn = 0; dn < 4; ++dn)
                out[ob + dn * 16 + fr] = f2bf(oacc[mt][dn][r] * lsum[mt][r]);
        }
}

// ---------------- global attention: MFMA flash, 128 q-rows/block, 4 waves ----------------
__global__ __launch_bounds__(256) void attn_global_mfma(const ushort* __restrict__ qkv,
                                                        ushort* __restrict__ out) {
    __shared__ ushort Klds[64 * 64];
    __shared__ ushort Vtlds[64 * 64];
    __shared__ ushort Plds[4][32 * 64];
    int tid  = threadIdx.x;
    int lane = tid & 63, w = tid >> 6;
    int fr = lane & 15, g = lane >> 4;
    int qtile = blockIdx.x & 7;
    int bh = blockIdx.x >> 3;
    int h = bh & 7, b = bh >> 3;
    const size_t bbase = (size_t)b * Ss * (3 * Ee);
    const ushort* qp = qkv + bbase + h * Dh;
    const ushort* kbase = qkv + bbase + Ee + h * Dh;
    const ushort* vbase = qkv + bbase + 2 * Ee + h * Dh;

    i32x4 qf[2][2];
    int q0 = qtile * 128 + w * 32;
    #pragma unroll
    for (int mt = 0; mt < 2; ++mt)
        #pragma unroll
        for (int kb = 0; kb < 2; ++kb)
            qf[mt][kb] = *(const i32x4*)(qp + (size_t)(q0 + mt * 16 + fr) * (3 * Ee) + kb * 32 + g * 8);

    f32x4 oacc[2][4] = {};
    f32x4 lsum[2] = {};
    ushort* Pw = Plds[w];

    for (int kt = 0; kt < 16; ++kt) {
        int kv0 = kt * 64;
        i32x4 kr[2], vr[2];
        #pragma unroll
        for (int u = 0; u < 2; ++u) {
            int c = tid + u * 256;
            int row = c >> 3, col8 = c & 7;
            kr[u] = *(const i32x4*)(kbase + (size_t)(kv0 + row) * (3 * Ee) + col8 * 8);
            vr[u] = *(const i32x4*)(vbase + (size_t)(kv0 + row) * (3 * Ee) + col8 * 8);
        }
        __syncthreads();
        #pragma unroll
        for (int u = 0; u < 2; ++u) {
            int c = tid + u * 256;
            int row = c >> 3, col8 = c & 7;
            int kidx = (row * 64 + col8 * 8) ^ ((row & 7) << 3);
            *(i32x4*)(Klds + kidx) = kr[u];
            ushort tmp[8];
            *(i32x4*)tmp = vr[u];
            #pragma unroll
            for (int j = 0; j < 8; ++j) {
                int d = col8 * 8 + j;
                Vtlds[(d * 64 + row) ^ ((d & 7) << 3)] = tmp[j];
            }
        }
        __syncthreads();

        f32x4 sacc[2][4] = {};
        i32x4 kf[4][2];
        #pragma unroll
        for (int nt = 0; nt < 4; ++nt) {
            int kvl = nt * 16 + fr;
            #pragma unroll
            for (int kb = 0; kb < 2; ++kb)
                kf[nt][kb] = *(const i32x4*)(Klds + ((kvl * 64 + kb * 32 + g * 8) ^ ((kvl & 7) << 3)));
        }
        #pragma unroll
        for (int mt = 0; mt < 2; ++mt)
            #pragma unroll
            for (int nt = 0; nt < 4; ++nt)
                #pragma unroll
                for (int kb = 0; kb < 2; ++kb)
                    asm("v_mfma_f32_16x16x32_bf16 %0, %1, %2, %0"
                        : "+v"(sacc[mt][nt]) : "v"(qf[mt][kb]), "v"(kf[nt][kb]));

        #pragma unroll
        for (int mt = 0; mt < 2; ++mt) {
            #pragma unroll
            for (int r = 0; r < 4; ++r) {
                int ql = mt * 16 + g * 4 + r;
                int sw = (ql & 7) << 3;
                float e0 = __expf(sacc[mt][0][r] * 0.125f);
                float e1 = __expf(sacc[mt][1][r] * 0.125f);
                float e2 = __expf(sacc[mt][2][r] * 0.125f);
                float e3 = __expf(sacc[mt][3][r] * 0.125f);
                Pw[(ql * 64 +  0 + fr) ^ sw] = f2bf(e0);
                Pw[(ql * 64 + 16 + fr) ^ sw] = f2bf(e1);
                Pw[(ql * 64 + 32 + fr) ^ sw] = f2bf(e2);
                Pw[(ql * 64 + 48 + fr) ^ sw] = f2bf(e3);
                lsum[mt][r] += (e0 + e1) + (e2 + e3);
            }
        }

        i32x4 pa[2][2], vf[4][2];
        #pragma unroll
        for (int mt = 0; mt < 2; ++mt) {
            int ql = mt * 16 + fr;
            #pragma unroll
            for (int kb = 0; kb < 2; ++kb)
                pa[mt][kb] = *(const i32x4*)(Pw + ((ql * 64 + kb * 32 + g * 8) ^ ((ql & 7) << 3)));
        }
        #pragma unroll
        for (int dn = 0; dn < 4; ++dn) {
            int d = dn * 16 + fr;
            #pragma unroll
            for (int kb = 0; kb < 2; ++kb)
                vf[dn][kb] = *(const i32x4*)(Vtlds + ((d * 64 + kb * 32 + g * 8) ^ ((d & 7) << 3)));
        }
        #pragma unroll
        for (int mt = 0; mt < 2; ++mt)
            #pragma unroll
            for (int dn = 0; dn < 4; ++dn)
                #pragma unroll
                for (int kb = 0; kb < 2; ++kb)
                    asm("v_mfma_f32_16x16x32_bf16 %0, %1, %2, %0"
                        : "+v"(oacc[mt][dn]) : "v"(pa[mt][kb]), "v"(vf[dn][kb]));
    }

    #pragma unroll
    for (int mt = 0; mt < 2; ++mt)
        #pragma unroll
        for (int r = 0; r < 4; ++r) {
            float s = lsum[mt][r];
            s += __shfl_xor(s, 1); s += __shfl_xor(s, 2);
            s += __shfl_xor(s, 4); s += __shfl_xor(s, 8);
            lsum[mt][r] = 1.f / s;
        }

    #pragma unroll
    for (int mt = 0; mt < 2; ++mt)
        #pragma unroll
        for (int r = 0; r < 4; ++r) {
            int qg = q0 + mt * 16 + g * 4 + r;
            size_t ob = (size_t)(b * Ss + qg) * Ee + h * Dh;
            #pragma unroll
            for (int dn = 0; dn < 4; ++dn)
                out[ob + dn * 16 + fr] = f2bf(oacc[mt][dn][r] * lsum[mt][r]);
        }
}

// ---------------- fused residual(3-way) + LayerNorm, dual write (bf16 + f32) ----------------
__global__ __launch_bounds__(256) void ln_add3(const float* __restrict__ x,
                                               const float* __restrict__ p1,
                                               const float* __restrict__ p2,
                                               const float* __restrict__ gam,
                                               const float* __restrict__ bet,
                                               ushort* __restrict__ yb,
                                               float* __restrict__ yf) {
    int row  = blockIdx.x * 4 + (threadIdx.x >> 6);
    int lane = threadIdx.x & 63;
    size_t off = (size_t)row * Ee + lane * 8;
    float hv[8];
    float4 a0 = *(const float4*)(x + off),  a1 = *(const float4*)(x + off + 4);
    float4 b0 = *(const float4*)(p1 + off), b1 = *(const float4*)(p1 + off + 4);
    float4 c0 = *(const float4*)(p2 + off), c1 = *(const float4*)(p2 + off + 4);
    hv[0] = a0.x + b0.x + c0.x; hv[1] = a0.y + b0.y + c0.y;
    hv[2] = a0.z + b0.z + c0.z; hv[3] = a0.w + b0.w + c0.w;
    hv[4] = a1.x + b1.x + c1.x; hv[5] = a1.y + b1.y + c1.y;
    hv[6] = a1.z + b1.z + c1.z; hv[7] = a1.w + b1.w + c1.w;
    float s = 0.f;
    #pragma unroll
    for (int i = 0; i < 8; ++i) s += hv[i];
    #pragma unroll
    for (int o = 32; o; o >>= 1) s += __shfl_xor(s, o);
    float mu = s * (1.f / Ee);
    float vs = 0.f;
    #pragma unroll
    for (int i = 0; i < 8; ++i) { float d = hv[i] - mu; vs += d * d; }
    #pragma unroll
    for (int o = 32; o; o >>= 1) vs += __shfl_xor(vs, o);
    float rs = rsqrtf(vs * (1.f / Ee) + EPSv);
    #pragma unroll
    for (int i = 0; i < 8; ++i) {
        float yv = (hv[i] - mu) * rs * gam[lane * 8 + i] + bet[lane * 8 + i];
        yf[off + i] = yv;
        yb[off + i] = f2bf(yv);
    }
}

// ---------------- fused residual(2-way) + LayerNorm -> f32 out ----------------
__global__ __launch_bounds__(256) void ln_add2(const float* __restrict__ a,
                                               const float* __restrict__ bsrc,
                                               const float* __restrict__ gam,
                                               const float* __restrict__ bet,
                                               float* __restrict__ outp) {
    int row  = blockIdx.x * 4 + (threadIdx.x >> 6);
    int lane = threadIdx.x & 63;
    size_t off = (size_t)row * Ee + lane * 8;
    float hv[8];
    float4 a0 = *(const float4*)(a + off),    a1 = *(const float4*)(a + off + 4);
    float4 b0 = *(const float4*)(bsrc + off), b1 = *(const float4*)(bsrc + off + 4);
    hv[0] = a0.x + b0.x; hv[1] = a0.y + b0.y; hv[2] = a0.z + b0.z; hv[3] = a0.w + b0.w;
    hv[4] = a1.x + b1.x; hv[5] = a1.y + b1.y; hv[6] = a1.z + b1.z; hv[7] = a1.w + b1.w;
    float s = 0.f;
    #pragma unroll
    for (int i = 0; i < 8; ++i) s += hv[i];
    #pragma unroll
    for (int o = 32; o; o >>= 1) s += __shfl_xor(s, o);
    float mu = s * (1.f / Ee);
    float vs = 0.f;
    #pragma unroll
    for (int i = 0; i < 8; ++i) { float d = hv[i] - mu; vs += d * d; }
    #pragma unroll
    for (int o = 32; o; o >>= 1) vs += __shfl_xor(vs, o);
    float rs = rsqrtf(vs * (1.f / Ee) + EPSv);
    #pragma unroll
    for (int i = 0; i < 8; ++i)
        outp[off + i] = (hv[i] - mu) * rs * gam[lane * 8 + i] + bet[lane * 8 + i];
}

extern "C" void kernel_launch(void* const* d_in, const int* in_sizes, int n_in,
                              void* d_out, int out_size, void* d_ws, size_t ws_size,
                              hipStream_t stream) {
    const float* x      = (const float*)d_in[0];
    const float* l_in_w = (const float*)d_in[1];
    const float* l_in_b = (const float*)d_in[2];
    const float* l_out_w= (const float*)d_in[3];
    const float* l_out_b= (const float*)d_in[4];
    const float* g_in_w = (const float*)d_in[5];
    const float* g_in_b = (const float*)d_in[6];
    const float* g_out_w= (const float*)d_in[7];
    const float* g_out_b= (const float*)d_in[8];
    const float* ffn_w1 = (const float*)d_in[9];
    const float* ffn_b1 = (const float*)d_in[10];
    const float* ffn_w2 = (const float*)d_in[11];
    const float* ffn_b2 = (const float*)d_in[12];
    const float* ln1_g  = (const float*)d_in[13];
    const float* ln1_b  = (const float*)d_in[14];
    const float* ln2_g  = (const float*)d_in[15];
    const float* ln2_b  = (const float*)d_in[16];

    char* ws = (char*)d_ws;
    ushort* xb       = (ushort*)(ws + 0);          // 8.39 MB
    ushort* wb       = (ushort*)(ws + 8388608);    // 8.39 MB of bf16 weights
    ushort* l_in_wb  = wb;
    ushort* g_in_wb  = wb + 786432;
    ushort* l_out_wb = wb + 1572864;
    ushort* g_out_wb = wb + 1835008;
    ushort* w1b      = wb + 2097152;
    ushort* w2b      = wb + 3145728;
    ushort* qkvLb    = (ushort*)(ws + 16777216);   // 25.2 MB
    ushort* qkvGb    = (ushort*)(ws + 41943040);   // 25.2 MB
    ushort* attnLb   = (ushort*)(ws + 67108864);   // 8.39 MB
    ushort* attnGb   = (ushort*)(ws + 75497472);   // 8.39 MB
    float*  projL    = (float*)(ws + 16777216);    // reuse qkvL (dead after attn_local)
    float*  projG    = (float*)(ws + 33554432);    // reuse qkvL tail + qkvG head (dead)
    ushort* y1b      = (ushort*)(ws + 50331648);   // reuse qkvG mid (dead)
    float*  y1f      = (float*)(ws + 58720256);    // reuse qkvG tail + attnL (dead)
    ushort* ffn1b    = (ushort*)(ws + 16777216);   // reuse projL/projG (dead after ln1)
    float*  ffn2f    = (float*)(ws + 75497472);    // reuse attnG (dead) + fresh tail

    const int M = Bb * Ss;   // 8192

    auto cvt = [&](const float* in, ushort* out, int n) {
        int n4 = n / 4;
        cvt_f32_bf16<<<dim3((n4 + 255) / 256), dim3(256), 0, stream>>>(in, out, n4);
    };
    cvt(x,       xb,       Bb * Ss * Ee);
    cvt(l_in_w,  l_in_wb,  3 * Ee * Ee);
    cvt(g_in_w,  g_in_wb,  3 * Ee * Ee);
    cvt(l_out_w, l_out_wb, Ee * Ee);
    cvt(g_out_w, g_out_wb, Ee * Ee);
    cvt(ffn_w1,  w1b,      FFNd * Ee);
    cvt(ffn_w2,  w2b,      Ee * FFNd);

    // QKV projections (bf16 out)
    gemm_bt<true, false><<<dim3((3 * Ee) / 128, M / 128), 256, 0, stream>>>(
        xb, l_in_wb, l_in_b, qkvLb, M, 3 * Ee, Ee);
    gemm_bt<true, false><<<dim3((3 * Ee) / 128, M / 128), 256, 0, stream>>>(
        xb, g_in_wb, g_in_b, qkvGb, M, 3 * Ee, Ee);

    // attention
    attn_local_mfma<<<dim3(Bb * Hh * (Ss / 128)), 256, 0, stream>>>(qkvLb, attnLb);
    attn_global_mfma<<<dim3(Bb * Hh * (Ss / 128)), 256, 0, stream>>>(qkvGb, attnGb);

    // output projections (f32 out)
    gemm_bt<false, false><<<dim3(Ee / 128, M / 128), 256, 0, stream>>>(
        attnLb, l_out_wb, l_out_b, projL, M, Ee, Ee);
    gemm_bt<false, false><<<dim3(Ee / 128, M / 128), 256, 0, stream>>>(
        attnGb, g_out_wb, g_out_b, projG, M, Ee, Ee);

    // residual + LN1 (writes bf16 for FFN, f32 for residual-2)
    ln_add3<<<dim3(M / 4), 256, 0, stream>>>(x, projL, projG, ln1_g, ln1_b, y1b, y1f);

    // FFN
    gemm_bt<true, true><<<dim3(FFNd / 128, M / 128), 256, 0, stream>>>(
        y1b, w1b, ffn_b1, ffn1b, M, FFNd, Ee);
    gemm_bt<false, false><<<dim3(Ee / 128, M / 128), 256, 0, stream>>>(
        ffn1b, w2b, ffn_b2, ffn2f, M, Ee, FFNd);

    // residual + LN2 -> output
    ln_add2<<<dim3(M / 4), 256, 0, stream>>>(y1f, ffn2f, ln2_g, ln2_b, (float*)d_out);
}

// Round 9
// 318.977 us; speedup vs baseline: 13.6646x; 1.0640x over previous
//
#include <hip/hip_runtime.h>
#include <hip/hip_bf16.h>
#include <stdint.h>

#define Bb 8
#define Ss 1024
#define Ee 512
#define Hh 8
#define Dh 64
#define FFNd 2048
#define EPSv 1e-5f
#define QS 3072   // combined-QKV row stride (local 1536 | global 1536)

typedef float f32x4 __attribute__((ext_vector_type(4)));
typedef int   i32x4 __attribute__((ext_vector_type(4)));

__device__ inline float bf2f(ushort u) {
    uint32_t x = ((uint32_t)u) << 16; float f; __builtin_memcpy(&f, &x, 4); return f;
}
__device__ inline ushort f2bf(float f) {
    uint32_t x; __builtin_memcpy(&x, &f, 4);
    uint32_t r = (x + 0x7FFFu + ((x >> 16) & 1u)) >> 16; return (ushort)r;
}

// async global->LDS, 16B per lane; LDS dest = wave-uniform base + lane*16B
__device__ inline void gload16(const ushort* g, ushort* l) {
    __builtin_amdgcn_global_load_lds((const __attribute__((address_space(1))) void*)g,
                                     (__attribute__((address_space(3))) void*)l,
                                     16, 0, 0);
}

// V^T LDS swizzle: element V[kv][d] at Vtlds[(d*64+kv) ^ (((d&7)^((d>>3)&7))<<3)].
// Write (per thread: row=kv fixed, d=col8*8+j): swz=(j^col8)<<3 — col8 varies across
// lanes -> 2-way write (free).  Read (d=dn*16+fr): swz contains fr&7 -> b128 reads at
// structural minimum (same pattern as the verified K-fragment reads).
__device__ inline int vswz(int d, int kv) {
    return (d * 64 + kv) ^ ((((d & 7) ^ ((d >> 3) & 7)) & 7) << 3);
}

// ---------------- fused fp32 -> bf16 conversion (x + all weights, 1 launch) ----------------
__global__ __launch_bounds__(256) void cvt_all(const float* __restrict__ s0, const float* __restrict__ s1,
                                               const float* __restrict__ s2, const float* __restrict__ s3,
                                               const float* __restrict__ s4, const float* __restrict__ s5,
                                               const float* __restrict__ s6,
                                               ushort* __restrict__ dx, ushort* __restrict__ dw) {
    int bid = blockIdx.x;
    const float* src; ushort* dst; int boff;
    if (bid < 4096)      { src = s0; dst = dx;            boff = bid; }
    else if (bid < 4864) { src = s1; dst = dw;            boff = bid - 4096; }
    else if (bid < 5632) { src = s2; dst = dw + 786432;   boff = bid - 4864; }
    else if (bid < 5888) { src = s3; dst = dw + 1572864;  boff = bid - 5632; }
    else if (bid < 6144) { src = s4; dst = dw + 1835008;  boff = bid - 5888; }
    else if (bid < 7168) { src = s5; dst = dw + 2097152;  boff = bid - 6144; }
    else                 { src = s6; dst = dw + 3145728;  boff = bid - 7168; }
    int i = boff * 256 + threadIdx.x;
    float4 v = ((const float4*)src)[i];
    ushort4 o;
    o.x = f2bf(v.x); o.y = f2bf(v.y); o.z = f2bf(v.z); o.w = f2bf(v.w);
    ((ushort4*)dst)[i] = o;
}

// ---------------- bf16 GEMM: C[M,N] = A[M,K] @ B[N,K]^T + bias (+relu) ----------------
// 128x128 tile, BK=32, 256 threads (4 waves), global_load_lds width-16 staging (m97 structure).
template<bool OUT_BF16, bool RELU>
__global__ __launch_bounds__(256) void gemm_bt(const ushort* __restrict__ A,
                                               const ushort* __restrict__ Bm,
                                               const float* __restrict__ bias,
                                               const float* __restrict__ bias2, int nb1,
                                               void* __restrict__ C,
                                               int M, int N, int K) {
    __shared__ ushort Alds[128 * 32];
    __shared__ ushort Blds[128 * 32];
    int tid  = threadIdx.x;
    int lane = tid & 63, w = tid >> 6;
    int wr = w >> 1, wc = w & 1;
    int g  = lane >> 4, fr = lane & 15;
    int m0 = blockIdx.y * 128, n0 = blockIdx.x * 128;

    int lr4 = lane >> 2;
    int lc8 = (lane & 3) * 8;
    const ushort* gA0 = A  + (size_t)(m0 + (w * 2) * 16 + lr4) * K + lc8;
    const ushort* gA1 = gA0 + (size_t)16 * K;
    const ushort* gB0 = Bm + (size_t)(n0 + (w * 2) * 16 + lr4) * K + lc8;
    const ushort* gB1 = gB0 + (size_t)16 * K;
    ushort* lA0 = Alds + (w * 2) * 16 * 32;   // wave-uniform; HW adds lane*16B
    ushort* lA1 = lA0 + 16 * 32;
    ushort* lB0 = Blds + (w * 2) * 16 * 32;
    ushort* lB1 = lB0 + 16 * 32;

    f32x4 acc[4][4] = {};

    for (int kb = 0; kb < K; kb += 32) {
        __syncthreads();
        gload16(gA0 + kb, lA0);
        gload16(gA1 + kb, lA1);
        gload16(gB0 + kb, lB0);
        gload16(gB1 + kb, lB1);
        __syncthreads();
        i32x4 af[4], bfr[4];
        #pragma unroll
        for (int mt = 0; mt < 4; ++mt)
            af[mt] = *(const i32x4*)(Alds + (wr * 64 + mt * 16 + fr) * 32 + g * 8);
        #pragma unroll
        for (int nt = 0; nt < 4; ++nt)
            bfr[nt] = *(const i32x4*)(Blds + (wc * 64 + nt * 16 + fr) * 32 + g * 8);
        #pragma unroll
        for (int mt = 0; mt < 4; ++mt)
            #pragma unroll
            for (int nt = 0; nt < 4; ++nt)
                asm("v_mfma_f32_16x16x32_bf16 %0, %1, %2, %0"
                    : "+v"(acc[mt][nt]) : "v"(af[mt]), "v"(bfr[nt]));
    }

    #pragma unroll
    for (int mt = 0; mt < 4; ++mt) {
        int r0 = m0 + wr * 64 + mt * 16 + g * 4;
        #pragma unroll
        for (int nt = 0; nt < 4; ++nt) {
            int c = n0 + wc * 64 + nt * 16 + fr;
            float bv = c < nb1 ? bias[c] : bias2[c - nb1];
            #pragma unroll
            for (int r = 0; r < 4; ++r) {
                float v = acc[mt][nt][r] + bv;
                if (RELU) v = v > 0.f ? v : 0.f;
                if (OUT_BF16) ((ushort*)C)[(size_t)(r0 + r) * N + c] = f2bf(v);
                else          ((float*)C)[(size_t)(r0 + r) * N + c] = v;
            }
        }
    }
}

// ---------------- global attention: MFMA flash, 128 q-rows/block, 4 waves ----------------
// Scores bounded (~|s|<8 after *0.125): exp without max-subtract (validated rounds 1-3).
__global__ __launch_bounds__(256) void attn_global_mfma(const ushort* __restrict__ qkv,
                                                        ushort* __restrict__ out) {
    __shared__ ushort Klds[64 * 64];       // K[kv][d], XOR-swizzled (round-3 verified)
    __shared__ ushort Vtlds[64 * 64];      // V^T[d][kv], vswz layout
    __shared__ ushort Plds[4][32 * 64];    // per-wave P[q][kv], XOR-swizzled
    int tid  = threadIdx.x;
    int lane = tid & 63, w = tid >> 6;
    int fr = lane & 15, g = lane >> 4;
    int qtile = blockIdx.x & 7;
    int bh = blockIdx.x >> 3;
    int h = bh & 7, b = bh >> 3;
    const ushort* qp    = qkv + (size_t)b * Ss * QS + h * Dh;
    const ushort* kbase = qp + Ee;
    const ushort* vbase = qp + 2 * Ee;

    i32x4 qf[2][2];
    int q0 = qtile * 128 + w * 32;
    #pragma unroll
    for (int mt = 0; mt < 2; ++mt)
        #pragma unroll
        for (int kb = 0; kb < 2; ++kb)
            qf[mt][kb] = *(const i32x4*)(qp + (size_t)(q0 + mt * 16 + fr) * QS + kb * 32 + g * 8);

    f32x4 oacc[2][4] = {};
    f32x4 lsum[2] = {};
    ushort* Pw = Plds[w];

    i32x4 kr[2], vr[2];
    auto load_tile = [&](int kv0) {
        #pragma unroll
        for (int u = 0; u < 2; ++u) {
            int c = tid + u * 256;
            int row = c >> 3, col8 = c & 7;
            kr[u] = *(const i32x4*)(kbase + (size_t)(kv0 + row) * QS + col8 * 8);
            vr[u] = *(const i32x4*)(vbase + (size_t)(kv0 + row) * QS + col8 * 8);
        }
    };
    load_tile(0);

    for (int kt = 0; kt < 16; ++kt) {
        __syncthreads();   // previous tile's LDS reads complete
        #pragma unroll
        for (int u = 0; u < 2; ++u) {
            int c = tid + u * 256;
            int row = c >> 3, col8 = c & 7;
            int kidx = (row * 64 + col8 * 8) ^ ((row & 7) << 3);
            *(i32x4*)(Klds + kidx) = kr[u];
            ushort tmp[8];
            *(i32x4*)tmp = vr[u];
            #pragma unroll
            for (int j = 0; j < 8; ++j)
                Vtlds[vswz(col8 * 8 + j, row)] = tmp[j];
        }
        __syncthreads();   // staging visible
        if (kt < 15) load_tile((kt + 1) * 64);   // T14: issue next loads under compute

        // ---- QK^T: S[32q][64kv] ----
        f32x4 sacc[2][4] = {};
        i32x4 kf[4][2];
        #pragma unroll
        for (int nt = 0; nt < 4; ++nt) {
            int kvl = nt * 16 + fr;
            #pragma unroll
            for (int kb = 0; kb < 2; ++kb)
                kf[nt][kb] = *(const i32x4*)(Klds + ((kvl * 64 + kb * 32 + g * 8) ^ ((kvl & 7) << 3)));
        }
        #pragma unroll
        for (int mt = 0; mt < 2; ++mt)
            #pragma unroll
            for (int nt = 0; nt < 4; ++nt)
                #pragma unroll
                for (int kb = 0; kb < 2; ++kb)
                    asm("v_mfma_f32_16x16x32_bf16 %0, %1, %2, %0"
                        : "+v"(sacc[mt][nt]) : "v"(qf[mt][kb]), "v"(kf[nt][kb]));

        // ---- exp + P -> LDS (C/D layout: col=fr, row=g*4+r) ----
        #pragma unroll
        for (int mt = 0; mt < 2; ++mt) {
            #pragma unroll
            for (int r = 0; r < 4; ++r) {
                int ql = mt * 16 + g * 4 + r;
                int sw = (ql & 7) << 3;
                float e0 = __expf(sacc[mt][0][r] * 0.125f);
                float e1 = __expf(sacc[mt][1][r] * 0.125f);
                float e2 = __expf(sacc[mt][2][r] * 0.125f);
                float e3 = __expf(sacc[mt][3][r] * 0.125f);
                Pw[(ql * 64 +  0 + fr) ^ sw] = f2bf(e0);
                Pw[(ql * 64 + 16 + fr) ^ sw] = f2bf(e1);
                Pw[(ql * 64 + 32 + fr) ^ sw] = f2bf(e2);
                Pw[(ql * 64 + 48 + fr) ^ sw] = f2bf(e3);
                lsum[mt][r] += (e0 + e1) + (e2 + e3);
            }
        }

        // ---- PV: O += P[32q][64kv] @ V[64kv][64d] ----
        i32x4 pa[2][2], vf[4][2];
        #pragma unroll
        for (int mt = 0; mt < 2; ++mt) {
            int ql = mt * 16 + fr;
            #pragma unroll
            for (int kb = 0; kb < 2; ++kb)
                pa[mt][kb] = *(const i32x4*)(Pw + ((ql * 64 + kb * 32 + g * 8) ^ ((ql & 7) << 3)));
        }
        #pragma unroll
        for (int dn = 0; dn < 4; ++dn) {
            int d = dn * 16 + fr;
            #pragma unroll
            for (int kb = 0; kb < 2; ++kb)
                vf[dn][kb] = *(const i32x4*)(Vtlds + vswz(d, kb * 32 + g * 8));
        }
        #pragma unroll
        for (int mt = 0; mt < 2; ++mt)
            #pragma unroll
            for (int dn = 0; dn < 4; ++dn)
                #pragma unroll
                for (int kb = 0; kb < 2; ++kb)
                    asm("v_mfma_f32_16x16x32_bf16 %0, %1, %2, %0"
                        : "+v"(oacc[mt][dn]) : "v"(pa[mt][kb]), "v"(vf[dn][kb]));
    }

    #pragma unroll
    for (int mt = 0; mt < 2; ++mt)
        #pragma unroll
        for (int r = 0; r < 4; ++r) {
            float s = lsum[mt][r];
            s += __shfl_xor(s, 1); s += __shfl_xor(s, 2);
            s += __shfl_xor(s, 4); s += __shfl_xor(s, 8);
            lsum[mt][r] = 1.f / s;
        }

    #pragma unroll
    for (int mt = 0; mt < 2; ++mt)
        #pragma unroll
        for (int r = 0; r < 4; ++r) {
            int qg = q0 + mt * 16 + g * 4 + r;
            size_t ob = (size_t)(b * Ss + qg) * Ee + h * Dh;
            #pragma unroll
            for (int dn = 0; dn < 4; ++dn)
                out[ob + dn * 16 + fr] = f2bf(oacc[mt][dn][r] * lsum[mt][r]);
        }
}

// ---------------- local windowed attention: MFMA flash over the band tiles ----------------
__global__ __launch_bounds__(256) void attn_local_mfma(const ushort* __restrict__ qkv,
                                                       ushort* __restrict__ out) {
    __shared__ ushort Klds[64 * 64];
    __shared__ ushort Vtlds[64 * 64];
    __shared__ ushort Plds[4][32 * 64];
    int tid  = threadIdx.x;
    int lane = tid & 63, w = tid >> 6;
    int fr = lane & 15, g = lane >> 4;
    int qtile = blockIdx.x & 7;
    int bh = blockIdx.x >> 3;
    int h = bh & 7, b = bh >> 3;
    const ushort* qp    = qkv + (size_t)b * Ss * QS + h * Dh;
    const ushort* kbase = qp + Ee;
    const ushort* vbase = qp + 2 * Ee;

    i32x4 qf[2][2];
    int q0 = qtile * 128 + w * 32;
    #pragma unroll
    for (int mt = 0; mt < 2; ++mt)
        #pragma unroll
        for (int kb = 0; kb < 2; ++kb)
            qf[mt][kb] = *(const i32x4*)(qp + (size_t)(q0 + mt * 16 + fr) * QS + kb * 32 + g * 8);

    f32x4 oacc[2][4] = {};
    f32x4 lsum[2] = {};
    ushort* Pw = Plds[w];

    i32x4 kr[2], vr[2];
    auto load_tile = [&](int kv0) {
        #pragma unroll
        for (int u = 0; u < 2; ++u) {
            int c = tid + u * 256;
            int row = c >> 3, col8 = c & 7;
            kr[u] = *(const i32x4*)(kbase + (size_t)(kv0 + row) * QS + col8 * 8);
            vr[u] = *(const i32x4*)(vbase + (size_t)(kv0 + row) * QS + col8 * 8);
        }
    };

    int tq2 = qtile * 2;
    int kt0 = tq2 > 0 ? tq2 - 1 : 0;
    int kt1 = tq2 + 2 < 16 ? tq2 + 2 : 15;
    load_tile(kt0 * 64);

    for (int kt = kt0; kt <= kt1; ++kt) {
        int kv0 = kt * 64;
        __syncthreads();
        #pragma unroll
        for (int u = 0; u < 2; ++u) {
            int c = tid + u * 256;
            int row = c >> 3, col8 = c & 7;
            int kidx = (row * 64 + col8 * 8) ^ ((row & 7) << 3);
            *(i32x4*)(Klds + kidx) = kr[u];
            ushort tmp[8];
            *(i32x4*)tmp = vr[u];
            #pragma unroll
            for (int j = 0; j < 8; ++j)
                Vtlds[vswz(col8 * 8 + j, row)] = tmp[j];
        }
        __syncthreads();
        if (kt < kt1) load_tile((kt + 1) * 64);

        bool active = (kv0 <= q0 + 36) && (kv0 + 63 >= q0 - 5);
        if (active) {
            f32x4 sacc[2][4] = {};
            i32x4 kf[4][2];
            #pragma unroll
            for (int nt = 0; nt < 4; ++nt) {
                int kvl = nt * 16 + fr;
                #pragma unroll
                for (int kb = 0; kb < 2; ++kb)
                    kf[nt][kb] = *(const i32x4*)(Klds + ((kvl * 64 + kb * 32 + g * 8) ^ ((kvl & 7) << 3)));
            }
            #pragma unroll
            for (int mt = 0; mt < 2; ++mt)
                #pragma unroll
                for (int nt = 0; nt < 4; ++nt)
                    #pragma unroll
                    for (int kb = 0; kb < 2; ++kb)
                        asm("v_mfma_f32_16x16x32_bf16 %0, %1, %2, %0"
                            : "+v"(sacc[mt][nt]) : "v"(qf[mt][kb]), "v"(kf[nt][kb]));

            #pragma unroll
            for (int mt = 0; mt < 2; ++mt) {
                #pragma unroll
                for (int r = 0; r < 4; ++r) {
                    int ql = mt * 16 + g * 4 + r;
                    int sw = (ql & 7) << 3;
                    int d0 = (q0 + ql) - (kv0 + fr);
                    int d1 = d0 - 16, d2 = d0 - 32, d3 = d0 - 48;
                    float e0 = (d0 >= -5 && d0 <= 5) ? __expf(sacc[mt][0][r] * 0.125f) : 0.f;
                    float e1 = (d1 >= -5 && d1 <= 5) ? __expf(sacc[mt][1][r] * 0.125f) : 0.f;
                    float e2 = (d2 >= -5 && d2 <= 5) ? __expf(sacc[mt][2][r] * 0.125f) : 0.f;
                    float e3 = (d3 >= -5 && d3 <= 5) ? __expf(sacc[mt][3][r] * 0.125f) : 0.f;
                    Pw[(ql * 64 +  0 + fr) ^ sw] = f2bf(e0);
                    Pw[(ql * 64 + 16 + fr) ^ sw] = f2bf(e1);
                    Pw[(ql * 64 + 32 + fr) ^ sw] = f2bf(e2);
                    Pw[(ql * 64 + 48 + fr) ^ sw] = f2bf(e3);
                    lsum[mt][r] += (e0 + e1) + (e2 + e3);
                }
            }

            i32x4 pa[2][2], vf[4][2];
            #pragma unroll
            for (int mt = 0; mt < 2; ++mt) {
                int ql = mt * 16 + fr;
                #pragma unroll
                for (int kb = 0; kb < 2; ++kb)
                    pa[mt][kb] = *(const i32x4*)(Pw + ((ql * 64 + kb * 32 + g * 8) ^ ((ql & 7) << 3)));
            }
            #pragma unroll
            for (int dn = 0; dn < 4; ++dn) {
                int d = dn * 16 + fr;
                #pragma unroll
                for (int kb = 0; kb < 2; ++kb)
                    vf[dn][kb] = *(const i32x4*)(Vtlds + vswz(d, kb * 32 + g * 8));
            }
            #pragma unroll
            for (int mt = 0; mt < 2; ++mt)
                #pragma unroll
                for (int dn = 0; dn < 4; ++dn)
                    #pragma unroll
                    for (int kb = 0; kb < 2; ++kb)
                        asm("v_mfma_f32_16x16x32_bf16 %0, %1, %2, %0"
                            : "+v"(oacc[mt][dn]) : "v"(pa[mt][kb]), "v"(vf[dn][kb]));
        }
    }

    #pragma unroll
    for (int mt = 0; mt < 2; ++mt)
        #pragma unroll
        for (int r = 0; r < 4; ++r) {
            float s = lsum[mt][r];
            s += __shfl_xor(s, 1); s += __shfl_xor(s, 2);
            s += __shfl_xor(s, 4); s += __shfl_xor(s, 8);
            lsum[mt][r] = 1.f / s;
        }

    #pragma unroll
    for (int mt = 0; mt < 2; ++mt)
        #pragma unroll
        for (int r = 0; r < 4; ++r) {
            int qg = q0 + mt * 16 + g * 4 + r;
            size_t ob = (size_t)(b * Ss + qg) * Ee + h * Dh;
            #pragma unroll
            for (int dn = 0; dn < 4; ++dn)
                out[ob + dn * 16 + fr] = f2bf(oacc[mt][dn][r] * lsum[mt][r]);
        }
}

// ---------------- fused residual(3-way) + LayerNorm, dual write (bf16 + f32) ----------------
__global__ __launch_bounds__(256) void ln_add3(const float* __restrict__ x,
                                               const float* __restrict__ p1,
                                               const float* __restrict__ p2,
                                               const float* __restrict__ gam,
                                               const float* __restrict__ bet,
                                               ushort* __restrict__ yb,
                                               float* __restrict__ yf) {
    int row  = blockIdx.x * 4 + (threadIdx.x >> 6);
    int lane = threadIdx.x & 63;
    size_t off = (size_t)row * Ee + lane * 8;
    float hv[8];
    float4 a0 = *(const float4*)(x + off),  a1 = *(const float4*)(x + off + 4);
    float4 b0 = *(const float4*)(p1 + off), b1 = *(const float4*)(p1 + off + 4);
    float4 c0 = *(const float4*)(p2 + off), c1 = *(const float4*)(p2 + off + 4);
    hv[0] = a0.x + b0.x + c0.x; hv[1] = a0.y + b0.y + c0.y;
    hv[2] = a0.z + b0.z + c0.z; hv[3] = a0.w + b0.w + c0.w;
    hv[4] = a1.x + b1.x + c1.x; hv[5] = a1.y + b1.y + c1.y;
    hv[6] = a1.z + b1.z + c1.z; hv[7] = a1.w + b1.w + c1.w;
    float s = 0.f;
    #pragma unroll
    for (int i = 0; i < 8; ++i) s += hv[i];
    #pragma unroll
    for (int o = 32; o; o >>= 1) s += __shfl_xor(s, o);
    float mu = s * (1.f / Ee);
    float vs = 0.f;
    #pragma unroll
    for (int i = 0; i < 8; ++i) { float d = hv[i] - mu; vs += d * d; }
    #pragma unroll
    for (int o = 32; o; o >>= 1) vs += __shfl_xor(vs, o);
    float rs = rsqrtf(vs * (1.f / Ee) + EPSv);
    #pragma unroll
    for (int i = 0; i < 8; ++i) {
        float yv = (hv[i] - mu) * rs * gam[lane * 8 + i] + bet[lane * 8 + i];
        yf[off + i] = yv;
        yb[off + i] = f2bf(yv);
    }
}

// ---------------- fused residual(2-way) + LayerNorm -> f32 out ----------------
__global__ __launch_bounds__(256) void ln_add2(const float* __restrict__ a,
                                               const float* __restrict__ bsrc,
                                               const float* __restrict__ gam,
                                               const float* __restrict__ bet,
                                               float* __restrict__ outp) {
    int row  = blockIdx.x * 4 + (threadIdx.x >> 6);
    int lane = threadIdx.x & 63;
    size_t off = (size_t)row * Ee + lane * 8;
    float hv[8];
    float4 a0 = *(const float4*)(a + off),    a1 = *(const float4*)(a + off + 4);
    float4 b0 = *(const float4*)(bsrc + off), b1 = *(const float4*)(bsrc + off + 4);
    hv[0] = a0.x + b0.x; hv[1] = a0.y + b0.y; hv[2] = a0.z + b0.z; hv[3] = a0.w + b0.w;
    hv[4] = a1.x + b1.x; hv[5] = a1.y + b1.y; hv[6] = a1.z + b1.z; hv[7] = a1.w + b1.w;
    float s = 0.f;
    #pragma unroll
    for (int i = 0; i < 8; ++i) s += hv[i];
    #pragma unroll
    for (int o = 32; o; o >>= 1) s += __shfl_xor(s, o);
    float mu = s * (1.f / Ee);
    float vs = 0.f;
    #pragma unroll
    for (int i = 0; i < 8; ++i) { float d = hv[i] - mu; vs += d * d; }
    #pragma unroll
    for (int o = 32; o; o >>= 1) vs += __shfl_xor(vs, o);
    float rs = rsqrtf(vs * (1.f / Ee) + EPSv);
    #pragma unroll
    for (int i = 0; i < 8; ++i)
        outp[off + i] = (hv[i] - mu) * rs * gam[lane * 8 + i] + bet[lane * 8 + i];
}

extern "C" void kernel_launch(void* const* d_in, const int* in_sizes, int n_in,
                              void* d_out, int out_size, void* d_ws, size_t ws_size,
                              hipStream_t stream) {
    const float* x      = (const float*)d_in[0];
    const float* l_in_w = (const float*)d_in[1];
    const float* l_in_b = (const float*)d_in[2];
    const float* l_out_w= (const float*)d_in[3];
    const float* l_out_b= (const float*)d_in[4];
    const float* g_in_w = (const float*)d_in[5];
    const float* g_in_b = (const float*)d_in[6];
    const float* g_out_w= (const float*)d_in[7];
    const float* g_out_b= (const float*)d_in[8];
    const float* ffn_w1 = (const float*)d_in[9];
    const float* ffn_b1 = (const float*)d_in[10];
    const float* ffn_w2 = (const float*)d_in[11];
    const float* ffn_b2 = (const float*)d_in[12];
    const float* ln1_g  = (const float*)d_in[13];
    const float* ln1_b  = (const float*)d_in[14];
    const float* ln2_g  = (const float*)d_in[15];
    const float* ln2_b  = (const float*)d_in[16];

    char* ws = (char*)d_ws;
    // ---- workspace layout (peak 92.3 MB, liveness-checked) ----
    ushort* xb       = (ushort*)(ws + 0);          // 8.39 MB
    ushort* wb       = (ushort*)(ws + 8388608);    // 8.39 MB bf16 weights (contiguous)
    ushort* l_out_wb = wb + 1572864;
    ushort* w1b      = wb + 2097152;
    ushort* w2b      = wb + 3145728;
    // combined in_w [3072][512] = l_in_w rows then g_in_w rows, adjacent at wb
    ushort* g_out_wb = wb + 1835008;
    ushort* qkvb     = (ushort*)(ws + 16777216);   // 50.33 MB combined QKV [8192][3072]
    ushort* attnLb   = (ushort*)(ws + 67108864);   // 8.39 MB
    ushort* attnGb   = (ushort*)(ws + 75497472);   // 8.39 MB
    float*  projL    = (float*)(ws + 16777216);    // reuse qkvb (dead after attns)
    float*  projG    = (float*)(ws + 33554432);
    ushort* y1b      = (ushort*)(ws + 50331648);
    float*  y1f      = (float*)(ws + 58720256);    // overlaps attnLb (dead after projL)
    ushort* ffn1b    = (ushort*)(ws + 16777216);   // reuse projL/projG (dead after ln1)
    float*  ffn2f    = (float*)(ws + 75497472);    // reuse attnGb (dead after projG)

    const int M = Bb * Ss;   // 8192

    // one fused conversion launch (x + all weights)
    cvt_all<<<dim3(8192), dim3(256), 0, stream>>>(x, l_in_w, g_in_w, l_out_w, g_out_w,
                                                  ffn_w1, ffn_w2, xb, wb);

    // merged QKV projection: C[8192][3072], dual bias
    gemm_bt<true, false><<<dim3(24, 64), 256, 0, stream>>>(
        xb, wb, l_in_b, g_in_b, 1536, qkvb, M, QS, Ee);

    // attention (local half at +0, global half at +1536)
    attn_local_mfma<<<dim3(Bb * Hh * (Ss / 128)), 256, 0, stream>>>(qkvb, attnLb);
    attn_global_mfma<<<dim3(Bb * Hh * (Ss / 128)), 256, 0, stream>>>(qkvb + 1536, attnGb);

    // output projections (f32 out)
    gemm_bt<false, false><<<dim3(4, 64), 256, 0, stream>>>(
        attnLb, l_out_wb, l_out_b, l_out_b, Ee, projL, M, Ee, Ee);
    gemm_bt<false, false><<<dim3(4, 64), 256, 0, stream>>>(
        attnGb, g_out_wb, g_out_b, g_out_b, Ee, projG, M, Ee, Ee);

    // residual + LN1 (writes bf16 for FFN, f32 for residual-2)
    ln_add3<<<dim3(M / 4), 256, 0, stream>>>(x, projL, projG, ln1_g, ln1_b, y1b, y1f);

    // FFN
    gemm_bt<true, true><<<dim3(16, 64), 256, 0, stream>>>(
        y1b, w1b, ffn_b1, ffn_b1, FFNd, ffn1b, M, FFNd, Ee);
    gemm_bt<false, false><<<dim3(4, 64), 256, 0, stream>>>(
        ffn1b, w2b, ffn_b2, ffn_b2, Ee, ffn2f, M, Ee, FFNd);

    // residual + LN2 -> output
    ln_add2<<<dim3(M / 4), 256, 0, stream>>>(y1f, ffn2f, ln2_g, ln2_b, (float*)d_out);
}

// Round 10
// 296.607 us; speedup vs baseline: 14.6952x; 1.0754x over previous
//
#include <hip/hip_runtime.h>
#include <hip/hip_bf16.h>
#include <stdint.h>

#define Bb 8
#define Ss 1024
#define Ee 512
#define Hh 8
#define Dh 64
#define FFNd 2048
#define EPSv 1e-5f
#define QS 3072   // combined-QKV row stride (local 1536 | global 1536)
#define OS 1024   // concatenated attention-output row stride (local | global)

typedef float f32x4 __attribute__((ext_vector_type(4)));
typedef int   i32x4 __attribute__((ext_vector_type(4)));

__device__ inline float bf2f(ushort u) {
    uint32_t x = ((uint32_t)u) << 16; float f; __builtin_memcpy(&f, &x, 4); return f;
}
__device__ inline ushort f2bf(float f) {
    uint32_t x; __builtin_memcpy(&x, &f, 4);
    uint32_t r = (x + 0x7FFFu + ((x >> 16) & 1u)) >> 16; return (ushort)r;
}

// async global->LDS, 16B per lane; LDS dest = wave-uniform base + lane*16B
__device__ inline void gload16(const ushort* g, ushort* l) {
    __builtin_amdgcn_global_load_lds((const __attribute__((address_space(1))) void*)g,
                                     (__attribute__((address_space(3))) void*)l,
                                     16, 0, 0);
}

// V^T LDS swizzle (round-9 verified): V[kv][d] at Vtlds[(d*64+kv) ^ (((d&7)^((d>>3)&7))<<3)]
__device__ inline int vswz(int d, int kv) {
    return (d * 64 + kv) ^ ((((d & 7) ^ ((d >> 3) & 7)) & 7) << 3);
}

// ---------------- fused fp32 -> bf16 conversion (x + all weights, 1 launch) ----------------
// l_out_w / g_out_w are interleaved into w_cat[512][1024] = [l_out_w row | g_out_w row].
__device__ inline void cvt4_to(const float* src, int f, ushort* dst) {
    float4 v = *(const float4*)(src + f);
    ushort4 o;
    o.x = f2bf(v.x); o.y = f2bf(v.y); o.z = f2bf(v.z); o.w = f2bf(v.w);
    *(ushort4*)dst = o;
}
__global__ __launch_bounds__(256) void cvt_all(const float* __restrict__ s0, const float* __restrict__ s1,
                                               const float* __restrict__ s2, const float* __restrict__ s3,
                                               const float* __restrict__ s4, const float* __restrict__ s5,
                                               const float* __restrict__ s6,
                                               ushort* __restrict__ dx, ushort* __restrict__ dw) {
    int bid = blockIdx.x, tid = threadIdx.x;
    if (bid < 4096)      { int f = bid * 1024 + tid * 4;          cvt4_to(s0, f, dx + f); }
    else if (bid < 4864) { int f = (bid - 4096) * 1024 + tid * 4; cvt4_to(s1, f, dw + f); }
    else if (bid < 5632) { int f = (bid - 4864) * 1024 + tid * 4; cvt4_to(s2, f, dw + 786432 + f); }
    else if (bid < 5888) { int f = (bid - 5632) * 1024 + tid * 4; int n = f >> 9, k = f & 511;
                           cvt4_to(s3, f, dw + 1572864 + n * 1024 + k); }
    else if (bid < 6144) { int f = (bid - 5888) * 1024 + tid * 4; int n = f >> 9, k = f & 511;
                           cvt4_to(s4, f, dw + 1572864 + n * 1024 + 512 + k); }
    else if (bid < 7168) { int f = (bid - 6144) * 1024 + tid * 4; cvt4_to(s5, f, dw + 2097152 + f); }
    else                 { int f = (bid - 7168) * 1024 + tid * 4; cvt4_to(s6, f, dw + 3145728 + f); }
}

// ---------------- bf16 GEMM 128x128: C[M,N] = A[M,K] @ B[N,K]^T + bias (+relu) ----------------
template<bool OUT_BF16, bool RELU>
__global__ __launch_bounds__(256) void gemm_bt(const ushort* __restrict__ A,
                                               const ushort* __restrict__ Bm,
                                               const float* __restrict__ bias,
                                               const float* __restrict__ bias2, int nb1,
                                               void* __restrict__ C,
                                               int M, int N, int K) {
    __shared__ ushort Alds[128 * 32];
    __shared__ ushort Blds[128 * 32];
    int tid  = threadIdx.x;
    int lane = tid & 63, w = tid >> 6;
    int wr = w >> 1, wc = w & 1;
    int g  = lane >> 4, fr = lane & 15;
    int m0 = blockIdx.y * 128, n0 = blockIdx.x * 128;

    int lr4 = lane >> 2;
    int lc8 = (lane & 3) * 8;
    const ushort* gA0 = A  + (size_t)(m0 + (w * 2) * 16 + lr4) * K + lc8;
    const ushort* gA1 = gA0 + (size_t)16 * K;
    const ushort* gB0 = Bm + (size_t)(n0 + (w * 2) * 16 + lr4) * K + lc8;
    const ushort* gB1 = gB0 + (size_t)16 * K;
    ushort* lA0 = Alds + (w * 2) * 16 * 32;   // wave-uniform; HW adds lane*16B
    ushort* lA1 = lA0 + 16 * 32;
    ushort* lB0 = Blds + (w * 2) * 16 * 32;
    ushort* lB1 = lB0 + 16 * 32;

    f32x4 acc[4][4] = {};

    for (int kb = 0; kb < K; kb += 32) {
        __syncthreads();
        gload16(gA0 + kb, lA0);
        gload16(gA1 + kb, lA1);
        gload16(gB0 + kb, lB0);
        gload16(gB1 + kb, lB1);
        __syncthreads();
        i32x4 af[4], bfr[4];
        #pragma unroll
        for (int mt = 0; mt < 4; ++mt)
            af[mt] = *(const i32x4*)(Alds + (wr * 64 + mt * 16 + fr) * 32 + g * 8);
        #pragma unroll
        for (int nt = 0; nt < 4; ++nt)
            bfr[nt] = *(const i32x4*)(Blds + (wc * 64 + nt * 16 + fr) * 32 + g * 8);
        #pragma unroll
        for (int mt = 0; mt < 4; ++mt)
            #pragma unroll
            for (int nt = 0; nt < 4; ++nt)
                asm("v_mfma_f32_16x16x32_bf16 %0, %1, %2, %0"
                    : "+v"(acc[mt][nt]) : "v"(af[mt]), "v"(bfr[nt]));
    }

    #pragma unroll
    for (int mt = 0; mt < 4; ++mt) {
        int r0 = m0 + wr * 64 + mt * 16 + g * 4;
        #pragma unroll
        for (int nt = 0; nt < 4; ++nt) {
            int c = n0 + wc * 64 + nt * 16 + fr;
            float bv = c < nb1 ? bias[c] : bias2[c - nb1];
            #pragma unroll
            for (int r = 0; r < 4; ++r) {
                float v = acc[mt][nt][r] + bv;
                if (RELU) v = v > 0.f ? v : 0.f;
                if (OUT_BF16) ((ushort*)C)[(size_t)(r0 + r) * N + c] = f2bf(v);
                else          ((float*)C)[(size_t)(r0 + r) * N + c] = v;
            }
        }
    }
}

// ---------------- bf16 GEMM 64x128 (occupancy variant, f32 out) ----------------
// BM=64, BN=128, BK=32; 4 waves each own 64x32 (acc[4][2]); grid 2x the 128^2 tile
// => 2 blocks/CU at N=512 so barrier drains overlap across blocks.
template<bool SUMB>
__global__ __launch_bounds__(256) void gemm64(const ushort* __restrict__ A,
                                              const ushort* __restrict__ Bm,
                                              const float* __restrict__ bias,
                                              const float* __restrict__ bias2,
                                              float* __restrict__ C,
                                              int M, int N, int K) {
    __shared__ ushort Alds[64 * 32];
    __shared__ ushort Blds[128 * 32];
    int tid  = threadIdx.x;
    int lane = tid & 63, w = tid >> 6;
    int g  = lane >> 4, fr = lane & 15;
    int m0 = blockIdx.y * 64, n0 = blockIdx.x * 128;

    int lr4 = lane >> 2;
    int lc8 = (lane & 3) * 8;
    const ushort* gA  = A  + (size_t)(m0 + w * 16 + lr4) * K + lc8;
    const ushort* gB0 = Bm + (size_t)(n0 + w * 32 + lr4) * K + lc8;
    const ushort* gB1 = gB0 + (size_t)16 * K;
    ushort* lA  = Alds + w * 16 * 32;         // wave-uniform; HW adds lane*16B
    ushort* lB0 = Blds + w * 32 * 32;
    ushort* lB1 = lB0 + 16 * 32;

    f32x4 acc[4][2] = {};

    for (int kb = 0; kb < K; kb += 32) {
        __syncthreads();
        gload16(gA + kb, lA);
        gload16(gB0 + kb, lB0);
        gload16(gB1 + kb, lB1);
        __syncthreads();
        i32x4 af[4], bfr[2];
        #pragma unroll
        for (int mt = 0; mt < 4; ++mt)
            af[mt] = *(const i32x4*)(Alds + (mt * 16 + fr) * 32 + g * 8);
        #pragma unroll
        for (int nt = 0; nt < 2; ++nt)
            bfr[nt] = *(const i32x4*)(Blds + (w * 32 + nt * 16 + fr) * 32 + g * 8);
        #pragma unroll
        for (int mt = 0; mt < 4; ++mt)
            #pragma unroll
            for (int nt = 0; nt < 2; ++nt)
                asm("v_mfma_f32_16x16x32_bf16 %0, %1, %2, %0"
                    : "+v"(acc[mt][nt]) : "v"(af[mt]), "v"(bfr[nt]));
    }

    #pragma unroll
    for (int mt = 0; mt < 4; ++mt) {
        int r0 = m0 + mt * 16 + g * 4;
        #pragma unroll
        for (int nt = 0; nt < 2; ++nt) {
            int c = n0 + w * 32 + nt * 16 + fr;
            float bv = SUMB ? bias[c] + bias2[c] : bias[c];
            #pragma unroll
            for (int r = 0; r < 4; ++r)
                C[(size_t)(r0 + r) * N + c] = acc[mt][nt][r] + bv;
        }
    }
}

// ---------------- global attention: MFMA flash, 128 q-rows/block, 4 waves ----------------
// out: concatenated [8192][OS] buffer; caller passes base (+0 local / +512 global).
__global__ __launch_bounds__(256) void attn_global_mfma(const ushort* __restrict__ qkv,
                                                        ushort* __restrict__ out) {
    __shared__ ushort Klds[64 * 64];
    __shared__ ushort Vtlds[64 * 64];
    __shared__ ushort Plds[4][32 * 64];
    int tid  = threadIdx.x;
    int lane = tid & 63, w = tid >> 6;
    int fr = lane & 15, g = lane >> 4;
    int qtile = blockIdx.x & 7;
    int bh = blockIdx.x >> 3;
    int h = bh & 7, b = bh >> 3;
    const ushort* qp    = qkv + (size_t)b * Ss * QS + h * Dh;
    const ushort* kbase = qp + Ee;
    const ushort* vbase = qp + 2 * Ee;

    i32x4 qf[2][2];
    int q0 = qtile * 128 + w * 32;
    #pragma unroll
    for (int mt = 0; mt < 2; ++mt)
        #pragma unroll
        for (int kb = 0; kb < 2; ++kb)
            qf[mt][kb] = *(const i32x4*)(qp + (size_t)(q0 + mt * 16 + fr) * QS + kb * 32 + g * 8);

    f32x4 oacc[2][4] = {};
    f32x4 lsum[2] = {};
    ushort* Pw = Plds[w];

    i32x4 kr[2], vr[2];
    auto load_tile = [&](int kv0) {
        #pragma unroll
        for (int u = 0; u < 2; ++u) {
            int c = tid + u * 256;
            int row = c >> 3, col8 = c & 7;
            kr[u] = *(const i32x4*)(kbase + (size_t)(kv0 + row) * QS + col8 * 8);
            vr[u] = *(const i32x4*)(vbase + (size_t)(kv0 + row) * QS + col8 * 8);
        }
    };
    load_tile(0);

    for (int kt = 0; kt < 16; ++kt) {
        __syncthreads();
        #pragma unroll
        for (int u = 0; u < 2; ++u) {
            int c = tid + u * 256;
            int row = c >> 3, col8 = c & 7;
            int kidx = (row * 64 + col8 * 8) ^ ((row & 7) << 3);
            *(i32x4*)(Klds + kidx) = kr[u];
            ushort tmp[8];
            *(i32x4*)tmp = vr[u];
            #pragma unroll
            for (int j = 0; j < 8; ++j)
                Vtlds[vswz(col8 * 8 + j, row)] = tmp[j];
        }
        __syncthreads();
        if (kt < 15) load_tile((kt + 1) * 64);   // T14: next loads under compute

        f32x4 sacc[2][4] = {};
        i32x4 kf[4][2];
        #pragma unroll
        for (int nt = 0; nt < 4; ++nt) {
            int kvl = nt * 16 + fr;
            #pragma unroll
            for (int kb = 0; kb < 2; ++kb)
                kf[nt][kb] = *(const i32x4*)(Klds + ((kvl * 64 + kb * 32 + g * 8) ^ ((kvl & 7) << 3)));
        }
        #pragma unroll
        for (int mt = 0; mt < 2; ++mt)
            #pragma unroll
            for (int nt = 0; nt < 4; ++nt)
                #pragma unroll
                for (int kb = 0; kb < 2; ++kb)
                    asm("v_mfma_f32_16x16x32_bf16 %0, %1, %2, %0"
                        : "+v"(sacc[mt][nt]) : "v"(qf[mt][kb]), "v"(kf[nt][kb]));

        #pragma unroll
        for (int mt = 0; mt < 2; ++mt) {
            #pragma unroll
            for (int r = 0; r < 4; ++r) {
                int ql = mt * 16 + g * 4 + r;
                int sw = (ql & 7) << 3;
                float e0 = __expf(sacc[mt][0][r] * 0.125f);
                float e1 = __expf(sacc[mt][1][r] * 0.125f);
                float e2 = __expf(sacc[mt][2][r] * 0.125f);
                float e3 = __expf(sacc[mt][3][r] * 0.125f);
                Pw[(ql * 64 +  0 + fr) ^ sw] = f2bf(e0);
                Pw[(ql * 64 + 16 + fr) ^ sw] = f2bf(e1);
                Pw[(ql * 64 + 32 + fr) ^ sw] = f2bf(e2);
                Pw[(ql * 64 + 48 + fr) ^ sw] = f2bf(e3);
                lsum[mt][r] += (e0 + e1) + (e2 + e3);
            }
        }

        i32x4 pa[2][2], vf[4][2];
        #pragma unroll
        for (int mt = 0; mt < 2; ++mt) {
            int ql = mt * 16 + fr;
            #pragma unroll
            for (int kb = 0; kb < 2; ++kb)
                pa[mt][kb] = *(const i32x4*)(Pw + ((ql * 64 + kb * 32 + g * 8) ^ ((ql & 7) << 3)));
        }
        #pragma unroll
        for (int dn = 0; dn < 4; ++dn) {
            int d = dn * 16 + fr;
            #pragma unroll
            for (int kb = 0; kb < 2; ++kb)
                vf[dn][kb] = *(const i32x4*)(Vtlds + vswz(d, kb * 32 + g * 8));
        }
        #pragma unroll
        for (int mt = 0; mt < 2; ++mt)
            #pragma unroll
            for (int dn = 0; dn < 4; ++dn)
                #pragma unroll
                for (int kb = 0; kb < 2; ++kb)
                    asm("v_mfma_f32_16x16x32_bf16 %0, %1, %2, %0"
                        : "+v"(oacc[mt][dn]) : "v"(pa[mt][kb]), "v"(vf[dn][kb]));
    }

    #pragma unroll
    for (int mt = 0; mt < 2; ++mt)
        #pragma unroll
        for (int r = 0; r < 4; ++r) {
            float s = lsum[mt][r];
            s += __shfl_xor(s, 1); s += __shfl_xor(s, 2);
            s += __shfl_xor(s, 4); s += __shfl_xor(s, 8);
            lsum[mt][r] = 1.f / s;
        }

    #pragma unroll
    for (int mt = 0; mt < 2; ++mt)
        #pragma unroll
        for (int r = 0; r < 4; ++r) {
            int qg = q0 + mt * 16 + g * 4 + r;
            size_t ob = (size_t)(b * Ss + qg) * OS + h * Dh;
            #pragma unroll
            for (int dn = 0; dn < 4; ++dn)
                out[ob + dn * 16 + fr] = f2bf(oacc[mt][dn][r] * lsum[mt][r]);
        }
}

// ---------------- local windowed attention: MFMA flash over the band tiles ----------------
__global__ __launch_bounds__(256) void attn_local_mfma(const ushort* __restrict__ qkv,
                                                       ushort* __restrict__ out) {
    __shared__ ushort Klds[64 * 64];
    __shared__ ushort Vtlds[64 * 64];
    __shared__ ushort Plds[4][32 * 64];
    int tid  = threadIdx.x;
    int lane = tid & 63, w = tid >> 6;
    int fr = lane & 15, g = lane >> 4;
    int qtile = blockIdx.x & 7;
    int bh = blockIdx.x >> 3;
    int h = bh & 7, b = bh >> 3;
    const ushort* qp    = qkv + (size_t)b * Ss * QS + h * Dh;
    const ushort* kbase = qp + Ee;
    const ushort* vbase = qp + 2 * Ee;

    i32x4 qf[2][2];
    int q0 = qtile * 128 + w * 32;
    #pragma unroll
    for (int mt = 0; mt < 2; ++mt)
        #pragma unroll
        for (int kb = 0; kb < 2; ++kb)
            qf[mt][kb] = *(const i32x4*)(qp + (size_t)(q0 + mt * 16 + fr) * QS + kb * 32 + g * 8);

    f32x4 oacc[2][4] = {};
    f32x4 lsum[2] = {};
    ushort* Pw = Plds[w];

    i32x4 kr[2], vr[2];
    auto load_tile = [&](int kv0) {
        #pragma unroll
        for (int u = 0; u < 2; ++u) {
            int c = tid + u * 256;
            int row = c >> 3, col8 = c & 7;
            kr[u] = *(const i32x4*)(kbase + (size_t)(kv0 + row) * QS + col8 * 8);
            vr[u] = *(const i32x4*)(vbase + (size_t)(kv0 + row) * QS + col8 * 8);
        }
    };

    int tq2 = qtile * 2;
    int kt0 = tq2 > 0 ? tq2 - 1 : 0;
    int kt1 = tq2 + 2 < 16 ? tq2 + 2 : 15;
    load_tile(kt0 * 64);

    for (int kt = kt0; kt <= kt1; ++kt) {
        int kv0 = kt * 64;
        __syncthreads();
        #pragma unroll
        for (int u = 0; u < 2; ++u) {
            int c = tid + u * 256;
            int row = c >> 3, col8 = c & 7;
            int kidx = (row * 64 + col8 * 8) ^ ((row & 7) << 3);
            *(i32x4*)(Klds + kidx) = kr[u];
            ushort tmp[8];
            *(i32x4*)tmp = vr[u];
            #pragma unroll
            for (int j = 0; j < 8; ++j)
                Vtlds[vswz(col8 * 8 + j, row)] = tmp[j];
        }
        __syncthreads();
        if (kt < kt1) load_tile((kt + 1) * 64);

        bool active = (kv0 <= q0 + 36) && (kv0 + 63 >= q0 - 5);
        if (active) {
            f32x4 sacc[2][4] = {};
            i32x4 kf[4][2];
            #pragma unroll
            for (int nt = 0; nt < 4; ++nt) {
                int kvl = nt * 16 + fr;
                #pragma unroll
                for (int kb = 0; kb < 2; ++kb)
                    kf[nt][kb] = *(const i32x4*)(Klds + ((kvl * 64 + kb * 32 + g * 8) ^ ((kvl & 7) << 3)));
            }
            #pragma unroll
            for (int mt = 0; mt < 2; ++mt)
                #pragma unroll
                for (int nt = 0; nt < 4; ++nt)
                    #pragma unroll
                    for (int kb = 0; kb < 2; ++kb)
                        asm("v_mfma_f32_16x16x32_bf16 %0, %1, %2, %0"
                            : "+v"(sacc[mt][nt]) : "v"(qf[mt][kb]), "v"(kf[nt][kb]));

            #pragma unroll
            for (int mt = 0; mt < 2; ++mt) {
                #pragma unroll
                for (int r = 0; r < 4; ++r) {
                    int ql = mt * 16 + g * 4 + r;
                    int sw = (ql & 7) << 3;
                    int d0 = (q0 + ql) - (kv0 + fr);
                    int d1 = d0 - 16, d2 = d0 - 32, d3 = d0 - 48;
                    float e0 = (d0 >= -5 && d0 <= 5) ? __expf(sacc[mt][0][r] * 0.125f) : 0.f;
                    float e1 = (d1 >= -5 && d1 <= 5) ? __expf(sacc[mt][1][r] * 0.125f) : 0.f;
                    float e2 = (d2 >= -5 && d2 <= 5) ? __expf(sacc[mt][2][r] * 0.125f) : 0.f;
                    float e3 = (d3 >= -5 && d3 <= 5) ? __expf(sacc[mt][3][r] * 0.125f) : 0.f;
                    Pw[(ql * 64 +  0 + fr) ^ sw] = f2bf(e0);
                    Pw[(ql * 64 + 16 + fr) ^ sw] = f2bf(e1);
                    Pw[(ql * 64 + 32 + fr) ^ sw] = f2bf(e2);
                    Pw[(ql * 64 + 48 + fr) ^ sw] = f2bf(e3);
                    lsum[mt][r] += (e0 + e1) + (e2 + e3);
                }
            }

            i32x4 pa[2][2], vf[4][2];
            #pragma unroll
            for (int mt = 0; mt < 2; ++mt) {
                int ql = mt * 16 + fr;
                #pragma unroll
                for (int kb = 0; kb < 2; ++kb)
                    pa[mt][kb] = *(const i32x4*)(Pw + ((ql * 64 + kb * 32 + g * 8) ^ ((ql & 7) << 3)));
            }
            #pragma unroll
            for (int dn = 0; dn < 4; ++dn) {
                int d = dn * 16 + fr;
                #pragma unroll
                for (int kb = 0; kb < 2; ++kb)
                    vf[dn][kb] = *(const i32x4*)(Vtlds + vswz(d, kb * 32 + g * 8));
            }
            #pragma unroll
            for (int mt = 0; mt < 2; ++mt)
                #pragma unroll
                for (int dn = 0; dn < 4; ++dn)
                    #pragma unroll
                    for (int kb = 0; kb < 2; ++kb)
                        asm("v_mfma_f32_16x16x32_bf16 %0, %1, %2, %0"
                            : "+v"(oacc[mt][dn]) : "v"(pa[mt][kb]), "v"(vf[dn][kb]));
        }
    }

    #pragma unroll
    for (int mt = 0; mt < 2; ++mt)
        #pragma unroll
        for (int r = 0; r < 4; ++r) {
            float s = lsum[mt][r];
            s += __shfl_xor(s, 1); s += __shfl_xor(s, 2);
            s += __shfl_xor(s, 4); s += __shfl_xor(s, 8);
            lsum[mt][r] = 1.f / s;
        }

    #pragma unroll
    for (int mt = 0; mt < 2; ++mt)
        #pragma unroll
        for (int r = 0; r < 4; ++r) {
            int qg = q0 + mt * 16 + g * 4 + r;
            size_t ob = (size_t)(b * Ss + qg) * OS + h * Dh;
            #pragma unroll
            for (int dn = 0; dn < 4; ++dn)
                out[ob + dn * 16 + fr] = f2bf(oacc[mt][dn][r] * lsum[mt][r]);
        }
}

// ---------------- fused residual(2-way) + LayerNorm, dual write (bf16 + f32) ----------------
__global__ __launch_bounds__(256) void ln_add2_dw(const float* __restrict__ x,
                                                  const float* __restrict__ p1,
                                                  const float* __restrict__ gam,
                                                  const float* __restrict__ bet,
                                                  ushort* __restrict__ yb,
                                                  float* __restrict__ yf) {
    int row  = blockIdx.x * 4 + (threadIdx.x >> 6);
    int lane = threadIdx.x & 63;
    size_t off = (size_t)row * Ee + lane * 8;
    float hv[8];
    float4 a0 = *(const float4*)(x + off),  a1 = *(const float4*)(x + off + 4);
    float4 b0 = *(const float4*)(p1 + off), b1 = *(const float4*)(p1 + off + 4);
    hv[0] = a0.x + b0.x; hv[1] = a0.y + b0.y; hv[2] = a0.z + b0.z; hv[3] = a0.w + b0.w;
    hv[4] = a1.x + b1.x; hv[5] = a1.y + b1.y; hv[6] = a1.z + b1.z; hv[7] = a1.w + b1.w;
    float s = 0.f;
    #pragma unroll
    for (int i = 0; i < 8; ++i) s += hv[i];
    #pragma unroll
    for (int o = 32; o; o >>= 1) s += __shfl_xor(s, o);
    float mu = s * (1.f / Ee);
    float vs = 0.f;
    #pragma unroll
    for (int i = 0; i < 8; ++i) { float d = hv[i] - mu; vs += d * d; }
    #pragma unroll
    for (int o = 32; o; o >>= 1) vs += __shfl_xor(vs, o);
    float rs = rsqrtf(vs * (1.f / Ee) + EPSv);
    #pragma unroll
    for (int i = 0; i < 8; ++i) {
        float yv = (hv[i] - mu) * rs * gam[lane * 8 + i] + bet[lane * 8 + i];
        yf[off + i] = yv;
        yb[off + i] = f2bf(yv);
    }
}

// ---------------- fused residual(2-way) + LayerNorm -> f32 out ----------------
__global__ __launch_bounds__(256) void ln_add2(const float* __restrict__ a,
                                               const float* __restrict__ bsrc,
                                               const float* __restrict__ gam,
                                               const float* __restrict__ bet,
                                               float* __restrict__ outp) {
    int row  = blockIdx.x * 4 + (threadIdx.x >> 6);
    int lane = threadIdx.x & 63;
    size_t off = (size_t)row * Ee + lane * 8;
    float hv[8];
    float4 a0 = *(const float4*)(a + off),    a1 = *(const float4*)(a + off + 4);
    float4 b0 = *(const float4*)(bsrc + off), b1 = *(const float4*)(bsrc + off + 4);
    hv[0] = a0.x + b0.x; hv[1] = a0.y + b0.y; hv[2] = a0.z + b0.z; hv[3] = a0.w + b0.w;
    hv[4] = a1.x + b1.x; hv[5] = a1.y + b1.y; hv[6] = a1.z + b1.z; hv[7] = a1.w + b1.w;
    float s = 0.f;
    #pragma unroll
    for (int i = 0; i < 8; ++i) s += hv[i];
    #pragma unroll
    for (int o = 32; o; o >>= 1) s += __shfl_xor(s, o);
    float mu = s * (1.f / Ee);
    float vs = 0.f;
    #pragma unroll
    for (int i = 0; i < 8; ++i) { float d = hv[i] - mu; vs += d * d; }
    #pragma unroll
    for (int o = 32; o; o >>= 1) vs += __shfl_xor(vs, o);
    float rs = rsqrtf(vs * (1.f / Ee) + EPSv);
    #pragma unroll
    for (int i = 0; i < 8; ++i)
        outp[off + i] = (hv[i] - mu) * rs * gam[lane * 8 + i] + bet[lane * 8 + i];
}

extern "C" void kernel_launch(void* const* d_in, const int* in_sizes, int n_in,
                              void* d_out, int out_size, void* d_ws, size_t ws_size,
                              hipStream_t stream) {
    const float* x      = (const float*)d_in[0];
    const float* l_in_w = (const float*)d_in[1];
    const float* l_in_b = (const float*)d_in[2];
    const float* l_out_w= (const float*)d_in[3];
    const float* l_out_b= (const float*)d_in[4];
    const float* g_in_w = (const float*)d_in[5];
    const float* g_in_b = (const float*)d_in[6];
    const float* g_out_w= (const float*)d_in[7];
    const float* g_out_b= (const float*)d_in[8];
    const float* ffn_w1 = (const float*)d_in[9];
    const float* ffn_b1 = (const float*)d_in[10];
    const float* ffn_w2 = (const float*)d_in[11];
    const float* ffn_b2 = (const float*)d_in[12];
    const float* ln1_g  = (const float*)d_in[13];
    const float* ln1_b  = (const float*)d_in[14];
    const float* ln2_g  = (const float*)d_in[15];
    const float* ln2_b  = (const float*)d_in[16];

    char* ws = (char*)d_ws;
    // ---- workspace layout (peak 92.3 MB, liveness-checked) ----
    ushort* xb       = (ushort*)(ws + 0);          // 8.39 MB
    ushort* wb       = (ushort*)(ws + 8388608);    // 8.39 MB bf16 weights
    // wb+0:        in_w combined [3072][512] (l then g)
    ushort* w_cat    = wb + 1572864;               // [512][1024] = [l_out_w | g_out_w]
    ushort* w1b      = wb + 2097152;
    ushort* w2b      = wb + 3145728;
    ushort* qkvb     = (ushort*)(ws + 16777216);   // 50.33 MB combined QKV [8192][3072]
    ushort* attnCat  = (ushort*)(ws + 67108864);   // 16.78 MB [8192][1024] (local|global)
    float*  projM    = (float*)(ws + 16777216);    // reuse qkvb (dead after attns)
    ushort* y1b      = (ushort*)(ws + 50331648);   // reuse qkvb tail
    float*  y1f      = (float*)(ws + 58720256);    // reuse qkvb tail + attnCat head (dead after projM)
    ushort* ffn1b    = (ushort*)(ws + 16777216);   // reuse projM (dead after ln1)
    float*  ffn2f    = (float*)(ws + 75497472);    // reuse attnCat upper (dead after projM)

    const int M = Bb * Ss;   // 8192

    // one fused conversion launch (x + all weights; out-proj weights interleaved to w_cat)
    cvt_all<<<dim3(8192), dim3(256), 0, stream>>>(x, l_in_w, g_in_w, l_out_w, g_out_w,
                                                  ffn_w1, ffn_w2, xb, wb);

    // merged QKV projection: C[8192][3072], dual bias
    gemm_bt<true, false><<<dim3(24, 64), 256, 0, stream>>>(
        xb, wb, l_in_b, g_in_b, 1536, qkvb, M, QS, Ee);

    // attention -> concatenated [8192][1024] (local cols 0-511, global 512-1023)
    attn_local_mfma<<<dim3(Bb * Hh * (Ss / 128)), 256, 0, stream>>>(qkvb, attnCat);
    attn_global_mfma<<<dim3(Bb * Hh * (Ss / 128)), 256, 0, stream>>>(qkvb + 1536, attnCat + 512);

    // merged output projection: projM = [attnL|attnG] @ [l_out_w|g_out_w]^T + (l_b+g_b)
    gemm64<true><<<dim3(Ee / 128, M / 64), 256, 0, stream>>>(
        attnCat, w_cat, l_out_b, g_out_b, projM, M, Ee, 1024);

    // residual + LN1 (writes bf16 for FFN, f32 for residual-2)
    ln_add2_dw<<<dim3(M / 4), 256, 0, stream>>>(x, projM, ln1_g, ln1_b, y1b, y1f);

    // FFN
    gemm_bt<true, true><<<dim3(16, 64), 256, 0, stream>>>(
        y1b, w1b, ffn_b1, ffn_b1, FFNd, ffn1b, M, FFNd, Ee);
    gemm64<false><<<dim3(Ee / 128, M / 64), 256, 0, stream>>>(
        ffn1b, w2b, ffn_b2, ffn_b2, ffn2f, M, Ee, FFNd);

    // residual + LN2 -> output
    ln_add2<<<dim3(M / 4), 256, 0, stream>>>(y1f, ffn2f, ln2_g, ln2_b, (float*)d_out);
}

// Round 11
// 295.318 us; speedup vs baseline: 14.7593x; 1.0044x over previous
//
#include <hip/hip_runtime.h>
#include <hip/hip_bf16.h>
#include <stdint.h>

#define Bb 8
#define Ss 1024
#define Ee 512
#define Hh 8
#define Dh 64
#define FFNd 2048
#define EPSv 1e-5f
#define QS 3072   // combined-QKV row stride (local 1536 | global 1536)
#define OS 1024   // concatenated attention-output row stride (local | global)

typedef float f32x4 __attribute__((ext_vector_type(4)));
typedef int   i32x4 __attribute__((ext_vector_type(4)));

__device__ inline float bf2f(ushort u) {
    uint32_t x = ((uint32_t)u) << 16; float f; __builtin_memcpy(&f, &x, 4); return f;
}
__device__ inline ushort f2bf(float f) {
    uint32_t x; __builtin_memcpy(&x, &f, 4);
    uint32_t r = (x + 0x7FFFu + ((x >> 16) & 1u)) >> 16; return (ushort)r;
}

// async global->LDS, 16B per lane; LDS dest = wave-uniform base + lane*16B
__device__ inline void gload16(const ushort* g, ushort* l) {
    __builtin_amdgcn_global_load_lds((const __attribute__((address_space(1))) void*)g,
                                     (__attribute__((address_space(3))) void*)l,
                                     16, 0, 0);
}

// V^T LDS swizzle (round-9 verified): V[kv][d] at Vtlds[(d*64+kv) ^ (((d&7)^((d>>3)&7))<<3)]
__device__ inline int vswz(int d, int kv) {
    return (d * 64 + kv) ^ ((((d & 7) ^ ((d >> 3) & 7)) & 7) << 3);
}

// ---------------- fused fp32 -> bf16 conversion (x + all weights, 1 launch) ----------------
__device__ inline void cvt4_to(const float* src, int f, ushort* dst) {
    float4 v = *(const float4*)(src + f);
    ushort4 o;
    o.x = f2bf(v.x); o.y = f2bf(v.y); o.z = f2bf(v.z); o.w = f2bf(v.w);
    *(ushort4*)dst = o;
}
__global__ __launch_bounds__(256) void cvt_all(const float* __restrict__ s0, const float* __restrict__ s1,
                                               const float* __restrict__ s2, const float* __restrict__ s3,
                                               const float* __restrict__ s4, const float* __restrict__ s5,
                                               const float* __restrict__ s6,
                                               ushort* __restrict__ dx, ushort* __restrict__ dw) {
    int bid = blockIdx.x, tid = threadIdx.x;
    if (bid < 4096)      { int f = bid * 1024 + tid * 4;          cvt4_to(s0, f, dx + f); }
    else if (bid < 4864) { int f = (bid - 4096) * 1024 + tid * 4; cvt4_to(s1, f, dw + f); }
    else if (bid < 5632) { int f = (bid - 4864) * 1024 + tid * 4; cvt4_to(s2, f, dw + 786432 + f); }
    else if (bid < 5888) { int f = (bid - 5632) * 1024 + tid * 4; int n = f >> 9, k = f & 511;
                           cvt4_to(s3, f, dw + 1572864 + n * 1024 + k); }
    else if (bid < 6144) { int f = (bid - 5888) * 1024 + tid * 4; int n = f >> 9, k = f & 511;
                           cvt4_to(s4, f, dw + 1572864 + n * 1024 + 512 + k); }
    else if (bid < 7168) { int f = (bid - 6144) * 1024 + tid * 4; cvt4_to(s5, f, dw + 2097152 + f); }
    else                 { int f = (bid - 7168) * 1024 + tid * 4; cvt4_to(s6, f, dw + 3145728 + f); }
}

// ---------------- bf16 GEMM 128x128, double-buffered (T3 2-phase) ----------------
// stage(t+1) issued BEFORE compute(t); one barrier per K-step (compiler drains vmcnt+lgkm
// before s_barrier => publish). Buffer parity t&1; reuse safe: parity-(t+1) reads retired
// before the previous iteration's end barrier.
template<bool OUT_BF16, bool RELU>
__global__ __launch_bounds__(256) void gemm_bt(const ushort* __restrict__ A,
                                               const ushort* __restrict__ Bm,
                                               const float* __restrict__ bias,
                                               const float* __restrict__ bias2, int nb1,
                                               void* __restrict__ C,
                                               int M, int N, int K) {
    __shared__ ushort Alds[2][128 * 32];
    __shared__ ushort Blds[2][128 * 32];
    int tid  = threadIdx.x;
    int lane = tid & 63, w = tid >> 6;
    int wr = w >> 1, wc = w & 1;
    int g  = lane >> 4, fr = lane & 15;
    int m0 = blockIdx.y * 128, n0 = blockIdx.x * 128;

    int lr4 = lane >> 2;
    int lc8 = (lane & 3) * 8;
    const ushort* gA0 = A  + (size_t)(m0 + (w * 2) * 16 + lr4) * K + lc8;
    const ushort* gA1 = gA0 + (size_t)16 * K;
    const ushort* gB0 = Bm + (size_t)(n0 + (w * 2) * 16 + lr4) * K + lc8;
    const ushort* gB1 = gB0 + (size_t)16 * K;
    int offA0 = (w * 2) * 16 * 32;    // wave-uniform; HW adds lane*16B
    int offA1 = offA0 + 16 * 32;

    f32x4 acc[4][4] = {};
    const int nst = K >> 5;

    auto stage = [&](int t) {
        int kb = t << 5, bi = t & 1;
        gload16(gA0 + kb, Alds[bi] + offA0);
        gload16(gA1 + kb, Alds[bi] + offA1);
        gload16(gB0 + kb, Blds[bi] + offA0);
        gload16(gB1 + kb, Blds[bi] + offA1);
    };

    stage(0);
    __syncthreads();

    for (int t = 0; t < nst; ++t) {
        if (t + 1 < nst) stage(t + 1);        // next tile's loads fly under compute
        int bi = t & 1;
        i32x4 af[4], bfr[4];
        #pragma unroll
        for (int mt = 0; mt < 4; ++mt)
            af[mt] = *(const i32x4*)(Alds[bi] + (wr * 64 + mt * 16 + fr) * 32 + g * 8);
        #pragma unroll
        for (int nt = 0; nt < 4; ++nt)
            bfr[nt] = *(const i32x4*)(Blds[bi] + (wc * 64 + nt * 16 + fr) * 32 + g * 8);
        #pragma unroll
        for (int mt = 0; mt < 4; ++mt)
            #pragma unroll
            for (int nt = 0; nt < 4; ++nt)
                asm("v_mfma_f32_16x16x32_bf16 %0, %1, %2, %0"
                    : "+v"(acc[mt][nt]) : "v"(af[mt]), "v"(bfr[nt]));
        __syncthreads();                      // drains vmcnt (publish t+1) + lgkm
    }

    #pragma unroll
    for (int mt = 0; mt < 4; ++mt) {
        int r0 = m0 + wr * 64 + mt * 16 + g * 4;
        #pragma unroll
        for (int nt = 0; nt < 4; ++nt) {
            int c = n0 + wc * 64 + nt * 16 + fr;
            float bv = c < nb1 ? bias[c] : bias2[c - nb1];
            #pragma unroll
            for (int r = 0; r < 4; ++r) {
                float v = acc[mt][nt][r] + bv;
                if (RELU) v = v > 0.f ? v : 0.f;
                if (OUT_BF16) ((ushort*)C)[(size_t)(r0 + r) * N + c] = f2bf(v);
                else          ((float*)C)[(size_t)(r0 + r) * N + c] = v;
            }
        }
    }
}

// ---------------- bf16 GEMM 64x128, double-buffered (occupancy variant, f32 out) ----------------
template<bool SUMB>
__global__ __launch_bounds__(256) void gemm64(const ushort* __restrict__ A,
                                              const ushort* __restrict__ Bm,
                                              const float* __restrict__ bias,
                                              const float* __restrict__ bias2,
                                              float* __restrict__ C,
                                              int M, int N, int K) {
    __shared__ ushort Alds[2][64 * 32];
    __shared__ ushort Blds[2][128 * 32];
    int tid  = threadIdx.x;
    int lane = tid & 63, w = tid >> 6;
    int g  = lane >> 4, fr = lane & 15;
    int m0 = blockIdx.y * 64, n0 = blockIdx.x * 128;

    int lr4 = lane >> 2;
    int lc8 = (lane & 3) * 8;
    const ushort* gA  = A  + (size_t)(m0 + w * 16 + lr4) * K + lc8;
    const ushort* gB0 = Bm + (size_t)(n0 + w * 32 + lr4) * K + lc8;
    const ushort* gB1 = gB0 + (size_t)16 * K;
    int offA  = w * 16 * 32;
    int offB0 = w * 32 * 32;
    int offB1 = offB0 + 16 * 32;

    f32x4 acc[4][2] = {};
    const int nst = K >> 5;

    auto stage = [&](int t) {
        int kb = t << 5, bi = t & 1;
        gload16(gA + kb, Alds[bi] + offA);
        gload16(gB0 + kb, Blds[bi] + offB0);
        gload16(gB1 + kb, Blds[bi] + offB1);
    };

    stage(0);
    __syncthreads();

    for (int t = 0; t < nst; ++t) {
        if (t + 1 < nst) stage(t + 1);
        int bi = t & 1;
        i32x4 af[4], bfr[2];
        #pragma unroll
        for (int mt = 0; mt < 4; ++mt)
            af[mt] = *(const i32x4*)(Alds[bi] + (mt * 16 + fr) * 32 + g * 8);
        #pragma unroll
        for (int nt = 0; nt < 2; ++nt)
            bfr[nt] = *(const i32x4*)(Blds[bi] + (w * 32 + nt * 16 + fr) * 32 + g * 8);
        #pragma unroll
        for (int mt = 0; mt < 4; ++mt)
            #pragma unroll
            for (int nt = 0; nt < 2; ++nt)
                asm("v_mfma_f32_16x16x32_bf16 %0, %1, %2, %0"
                    : "+v"(acc[mt][nt]) : "v"(af[mt]), "v"(bfr[nt]));
        __syncthreads();
    }

    #pragma unroll
    for (int mt = 0; mt < 4; ++mt) {
        int r0 = m0 + mt * 16 + g * 4;
        #pragma unroll
        for (int nt = 0; nt < 2; ++nt) {
            int c = n0 + w * 32 + nt * 16 + fr;
            float bv = SUMB ? bias[c] + bias2[c] : bias[c];
            #pragma unroll
            for (int r = 0; r < 4; ++r)
                C[(size_t)(r0 + r) * N + c] = acc[mt][nt][r] + bv;
        }
    }
}

// ---------------- global attention: MFMA flash, 128 q-rows/block, 4 waves ----------------
__global__ __launch_bounds__(256) void attn_global_mfma(const ushort* __restrict__ qkv,
                                                        ushort* __restrict__ out) {
    __shared__ ushort Klds[64 * 64];
    __shared__ ushort Vtlds[64 * 64];
    __shared__ ushort Plds[4][32 * 64];
    int tid  = threadIdx.x;
    int lane = tid & 63, w = tid >> 6;
    int fr = lane & 15, g = lane >> 4;
    int qtile = blockIdx.x & 7;
    int bh = blockIdx.x >> 3;
    int h = bh & 7, b = bh >> 3;
    const ushort* qp    = qkv + (size_t)b * Ss * QS + h * Dh;
    const ushort* kbase = qp + Ee;
    const ushort* vbase = qp + 2 * Ee;

    i32x4 qf[2][2];
    int q0 = qtile * 128 + w * 32;
    #pragma unroll
    for (int mt = 0; mt < 2; ++mt)
        #pragma unroll
        for (int kb = 0; kb < 2; ++kb)
            qf[mt][kb] = *(const i32x4*)(qp + (size_t)(q0 + mt * 16 + fr) * QS + kb * 32 + g * 8);

    f32x4 oacc[2][4] = {};
    f32x4 lsum[2] = {};
    ushort* Pw = Plds[w];

    i32x4 kr[2], vr[2];
    auto load_tile = [&](int kv0) {
        #pragma unroll
        for (int u = 0; u < 2; ++u) {
            int c = tid + u * 256;
            int row = c >> 3, col8 = c & 7;
            kr[u] = *(const i32x4*)(kbase + (size_t)(kv0 + row) * QS + col8 * 8);
            vr[u] = *(const i32x4*)(vbase + (size_t)(kv0 + row) * QS + col8 * 8);
        }
    };
    load_tile(0);

    for (int kt = 0; kt < 16; ++kt) {
        __syncthreads();
        #pragma unroll
        for (int u = 0; u < 2; ++u) {
            int c = tid + u * 256;
            int row = c >> 3, col8 = c & 7;
            int kidx = (row * 64 + col8 * 8) ^ ((row & 7) << 3);
            *(i32x4*)(Klds + kidx) = kr[u];
            ushort tmp[8];
            *(i32x4*)tmp = vr[u];
            #pragma unroll
            for (int j = 0; j < 8; ++j)
                Vtlds[vswz(col8 * 8 + j, row)] = tmp[j];
        }
        __syncthreads();
        if (kt < 15) load_tile((kt + 1) * 64);   // T14: next loads under compute

        f32x4 sacc[2][4] = {};
        i32x4 kf[4][2];
        #pragma unroll
        for (int nt = 0; nt < 4; ++nt) {
            int kvl = nt * 16 + fr;
            #pragma unroll
            for (int kb = 0; kb < 2; ++kb)
                kf[nt][kb] = *(const i32x4*)(Klds + ((kvl * 64 + kb * 32 + g * 8) ^ ((kvl & 7) << 3)));
        }
        #pragma unroll
        for (int mt = 0; mt < 2; ++mt)
            #pragma unroll
            for (int nt = 0; nt < 4; ++nt)
                #pragma unroll
                for (int kb = 0; kb < 2; ++kb)
                    asm("v_mfma_f32_16x16x32_bf16 %0, %1, %2, %0"
                        : "+v"(sacc[mt][nt]) : "v"(qf[mt][kb]), "v"(kf[nt][kb]));

        #pragma unroll
        for (int mt = 0; mt < 2; ++mt) {
            #pragma unroll
            for (int r = 0; r < 4; ++r) {
                int ql = mt * 16 + g * 4 + r;
                int sw = (ql & 7) << 3;
                float e0 = __expf(sacc[mt][0][r] * 0.125f);
                float e1 = __expf(sacc[mt][1][r] * 0.125f);
                float e2 = __expf(sacc[mt][2][r] * 0.125f);
                float e3 = __expf(sacc[mt][3][r] * 0.125f);
                Pw[(ql * 64 +  0 + fr) ^ sw] = f2bf(e0);
                Pw[(ql * 64 + 16 + fr) ^ sw] = f2bf(e1);
                Pw[(ql * 64 + 32 + fr) ^ sw] = f2bf(e2);
                Pw[(ql * 64 + 48 + fr) ^ sw] = f2bf(e3);
                lsum[mt][r] += (e0 + e1) + (e2 + e3);
            }
        }

        i32x4 pa[2][2], vf[4][2];
        #pragma unroll
        for (int mt = 0; mt < 2; ++mt) {
            int ql = mt * 16 + fr;
            #pragma unroll
            for (int kb = 0; kb < 2; ++kb)
                pa[mt][kb] = *(const i32x4*)(Pw + ((ql * 64 + kb * 32 + g * 8) ^ ((ql & 7) << 3)));
        }
        #pragma unroll
        for (int dn = 0; dn < 4; ++dn) {
            int d = dn * 16 + fr;
            #pragma unroll
            for (int kb = 0; kb < 2; ++kb)
                vf[dn][kb] = *(const i32x4*)(Vtlds + vswz(d, kb * 32 + g * 8));
        }
        #pragma unroll
        for (int mt = 0; mt < 2; ++mt)
            #pragma unroll
            for (int dn = 0; dn < 4; ++dn)
                #pragma unroll
                for (int kb = 0; kb < 2; ++kb)
                    asm("v_mfma_f32_16x16x32_bf16 %0, %1, %2, %0"
                        : "+v"(oacc[mt][dn]) : "v"(pa[mt][kb]), "v"(vf[dn][kb]));
    }

    #pragma unroll
    for (int mt = 0; mt < 2; ++mt)
        #pragma unroll
        for (int r = 0; r < 4; ++r) {
            float s = lsum[mt][r];
            s += __shfl_xor(s, 1); s += __shfl_xor(s, 2);
            s += __shfl_xor(s, 4); s += __shfl_xor(s, 8);
            lsum[mt][r] = 1.f / s;
        }

    #pragma unroll
    for (int mt = 0; mt < 2; ++mt)
        #pragma unroll
        for (int r = 0; r < 4; ++r) {
            int qg = q0 + mt * 16 + g * 4 + r;
            size_t ob = (size_t)(b * Ss + qg) * OS + h * Dh;
            #pragma unroll
            for (int dn = 0; dn < 4; ++dn)
                out[ob + dn * 16 + fr] = f2bf(oacc[mt][dn][r] * lsum[mt][r]);
        }
}

// ---------------- local windowed attention: MFMA flash over the band tiles ----------------
__global__ __launch_bounds__(256) void attn_local_mfma(const ushort* __restrict__ qkv,
                                                       ushort* __restrict__ out) {
    __shared__ ushort Klds[64 * 64];
    __shared__ ushort Vtlds[64 * 64];
    __shared__ ushort Plds[4][32 * 64];
    int tid  = threadIdx.x;
    int lane = tid & 63, w = tid >> 6;
    int fr = lane & 15, g = lane >> 4;
    int qtile = blockIdx.x & 7;
    int bh = blockIdx.x >> 3;
    int h = bh & 7, b = bh >> 3;
    const ushort* qp    = qkv + (size_t)b * Ss * QS + h * Dh;
    const ushort* kbase = qp + Ee;
    const ushort* vbase = qp + 2 * Ee;

    i32x4 qf[2][2];
    int q0 = qtile * 128 + w * 32;
    #pragma unroll
    for (int mt = 0; mt < 2; ++mt)
        #pragma unroll
        for (int kb = 0; kb < 2; ++kb)
            qf[mt][kb] = *(const i32x4*)(qp + (size_t)(q0 + mt * 16 + fr) * QS + kb * 32 + g * 8);

    f32x4 oacc[2][4] = {};
    f32x4 lsum[2] = {};
    ushort* Pw = Plds[w];

    i32x4 kr[2], vr[2];
    auto load_tile = [&](int kv0) {
        #pragma unroll
        for (int u = 0; u < 2; ++u) {
            int c = tid + u * 256;
            int row = c >> 3, col8 = c & 7;
            kr[u] = *(const i32x4*)(kbase + (size_t)(kv0 + row) * QS + col8 * 8);
            vr[u] = *(const i32x4*)(vbase + (size_t)(kv0 + row) * QS + col8 * 8);
        }
    };

    int tq2 = qtile * 2;
    int kt0 = tq2 > 0 ? tq2 - 1 : 0;
    int kt1 = tq2 + 2 < 16 ? tq2 + 2 : 15;
    load_tile(kt0 * 64);

    for (int kt = kt0; kt <= kt1; ++kt) {
        int kv0 = kt * 64;
        __syncthreads();
        #pragma unroll
        for (int u = 0; u < 2; ++u) {
            int c = tid + u * 256;
            int row = c >> 3, col8 = c & 7;
            int kidx = (row * 64 + col8 * 8) ^ ((row & 7) << 3);
            *(i32x4*)(Klds + kidx) = kr[u];
            ushort tmp[8];
            *(i32x4*)tmp = vr[u];
            #pragma unroll
            for (int j = 0; j < 8; ++j)
                Vtlds[vswz(col8 * 8 + j, row)] = tmp[j];
        }
        __syncthreads();
        if (kt < kt1) load_tile((kt + 1) * 64);

        bool active = (kv0 <= q0 + 36) && (kv0 + 63 >= q0 - 5);
        if (active) {
            f32x4 sacc[2][4] = {};
            i32x4 kf[4][2];
            #pragma unroll
            for (int nt = 0; nt < 4; ++nt) {
                int kvl = nt * 16 + fr;
                #pragma unroll
                for (int kb = 0; kb < 2; ++kb)
                    kf[nt][kb] = *(const i32x4*)(Klds + ((kvl * 64 + kb * 32 + g * 8) ^ ((kvl & 7) << 3)));
            }
            #pragma unroll
            for (int mt = 0; mt < 2; ++mt)
                #pragma unroll
                for (int nt = 0; nt < 4; ++nt)
                    #pragma unroll
                    for (int kb = 0; kb < 2; ++kb)
                        asm("v_mfma_f32_16x16x32_bf16 %0, %1, %2, %0"
                            : "+v"(sacc[mt][nt]) : "v"(qf[mt][kb]), "v"(kf[nt][kb]));

            #pragma unroll
            for (int mt = 0; mt < 2; ++mt) {
                #pragma unroll
                for (int r = 0; r < 4; ++r) {
                    int ql = mt * 16 + g * 4 + r;
                    int sw = (ql & 7) << 3;
                    int d0 = (q0 + ql) - (kv0 + fr);
                    int d1 = d0 - 16, d2 = d0 - 32, d3 = d0 - 48;
                    float e0 = (d0 >= -5 && d0 <= 5) ? __expf(sacc[mt][0][r] * 0.125f) : 0.f;
                    float e1 = (d1 >= -5 && d1 <= 5) ? __expf(sacc[mt][1][r] * 0.125f) : 0.f;
                    float e2 = (d2 >= -5 && d2 <= 5) ? __expf(sacc[mt][2][r] * 0.125f) : 0.f;
                    float e3 = (d3 >= -5 && d3 <= 5) ? __expf(sacc[mt][3][r] * 0.125f) : 0.f;
                    Pw[(ql * 64 +  0 + fr) ^ sw] = f2bf(e0);
                    Pw[(ql * 64 + 16 + fr) ^ sw] = f2bf(e1);
                    Pw[(ql * 64 + 32 + fr) ^ sw] = f2bf(e2);
                    Pw[(ql * 64 + 48 + fr) ^ sw] = f2bf(e3);
                    lsum[mt][r] += (e0 + e1) + (e2 + e3);
                }
            }

            i32x4 pa[2][2], vf[4][2];
            #pragma unroll
            for (int mt = 0; mt < 2; ++mt) {
                int ql = mt * 16 + fr;
                #pragma unroll
                for (int kb = 0; kb < 2; ++kb)
                    pa[mt][kb] = *(const i32x4*)(Pw + ((ql * 64 + kb * 32 + g * 8) ^ ((ql & 7) << 3)));
            }
            #pragma unroll
            for (int dn = 0; dn < 4; ++dn) {
                int d = dn * 16 + fr;
                #pragma unroll
                for (int kb = 0; kb < 2; ++kb)
                    vf[dn][kb] = *(const i32x4*)(Vtlds + vswz(d, kb * 32 + g * 8));
            }
            #pragma unroll
            for (int mt = 0; mt < 2; ++mt)
                #pragma unroll
                for (int dn = 0; dn < 4; ++dn)
                    #pragma unroll
                    for (int kb = 0; kb < 2; ++kb)
                        asm("v_mfma_f32_16x16x32_bf16 %0, %1, %2, %0"
                            : "+v"(oacc[mt][dn]) : "v"(pa[mt][kb]), "v"(vf[dn][kb]));
        }
    }

    #pragma unroll
    for (int mt = 0; mt < 2; ++mt)
        #pragma unroll
        for (int r = 0; r < 4; ++r) {
            float s = lsum[mt][r];
            s += __shfl_xor(s, 1); s += __shfl_xor(s, 2);
            s += __shfl_xor(s, 4); s += __shfl_xor(s, 8);
            lsum[mt][r] = 1.f / s;
        }

    #pragma unroll
    for (int mt = 0; mt < 2; ++mt)
        #pragma unroll
        for (int r = 0; r < 4; ++r) {
            int qg = q0 + mt * 16 + g * 4 + r;
            size_t ob = (size_t)(b * Ss + qg) * OS + h * Dh;
            #pragma unroll
            for (int dn = 0; dn < 4; ++dn)
                out[ob + dn * 16 + fr] = f2bf(oacc[mt][dn][r] * lsum[mt][r]);
        }
}

// ---------------- fused residual(2-way) + LayerNorm, dual write (bf16 + f32) ----------------
__global__ __launch_bounds__(256) void ln_add2_dw(const float* __restrict__ x,
                                                  const float* __restrict__ p1,
                                                  const float* __restrict__ gam,
                                                  const float* __restrict__ bet,
                                                  ushort* __restrict__ yb,
                                                  float* __restrict__ yf) {
    int row  = blockIdx.x * 4 + (threadIdx.x >> 6);
    int lane = threadIdx.x & 63;
    size_t off = (size_t)row * Ee + lane * 8;
    float hv[8];
    float4 a0 = *(const float4*)(x + off),  a1 = *(const float4*)(x + off + 4);
    float4 b0 = *(const float4*)(p1 + off), b1 = *(const float4*)(p1 + off + 4);
    hv[0] = a0.x + b0.x; hv[1] = a0.y + b0.y; hv[2] = a0.z + b0.z; hv[3] = a0.w + b0.w;
    hv[4] = a1.x + b1.x; hv[5] = a1.y + b1.y; hv[6] = a1.z + b1.z; hv[7] = a1.w + b1.w;
    float s = 0.f;
    #pragma unroll
    for (int i = 0; i < 8; ++i) s += hv[i];
    #pragma unroll
    for (int o = 32; o; o >>= 1) s += __shfl_xor(s, o);
    float mu = s * (1.f / Ee);
    float vs = 0.f;
    #pragma unroll
    for (int i = 0; i < 8; ++i) { float d = hv[i] - mu; vs += d * d; }
    #pragma unroll
    for (int o = 32; o; o >>= 1) vs += __shfl_xor(vs, o);
    float rs = rsqrtf(vs * (1.f / Ee) + EPSv);
    #pragma unroll
    for (int i = 0; i < 8; ++i) {
        float yv = (hv[i] - mu) * rs * gam[lane * 8 + i] + bet[lane * 8 + i];
        yf[off + i] = yv;
        yb[off + i] = f2bf(yv);
    }
}

// ---------------- fused residual(2-way) + LayerNorm -> f32 out ----------------
__global__ __launch_bounds__(256) void ln_add2(const float* __restrict__ a,
                                               const float* __restrict__ bsrc,
                                               const float* __restrict__ gam,
                                               const float* __restrict__ bet,
                                               float* __restrict__ outp) {
    int row  = blockIdx.x * 4 + (threadIdx.x >> 6);
    int lane = threadIdx.x & 63;
    size_t off = (size_t)row * Ee + lane * 8;
    float hv[8];
    float4 a0 = *(const float4*)(a + off),    a1 = *(const float4*)(a + off + 4);
    float4 b0 = *(const float4*)(bsrc + off), b1 = *(const float4*)(bsrc + off + 4);
    hv[0] = a0.x + b0.x; hv[1] = a0.y + b0.y; hv[2] = a0.z + b0.z; hv[3] = a0.w + b0.w;
    hv[4] = a1.x + b1.x; hv[5] = a1.y + b1.y; hv[6] = a1.z + b1.z; hv[7] = a1.w + b1.w;
    float s = 0.f;
    #pragma unroll
    for (int i = 0; i < 8; ++i) s += hv[i];
    #pragma unroll
    for (int o = 32; o; o >>= 1) s += __shfl_xor(s, o);
    float mu = s * (1.f / Ee);
    float vs = 0.f;
    #pragma unroll
    for (int i = 0; i < 8; ++i) { float d = hv[i] - mu; vs += d * d; }
    #pragma unroll
    for (int o = 32; o; o >>= 1) vs += __shfl_xor(vs, o);
    float rs = rsqrtf(vs * (1.f / Ee) + EPSv);
    #pragma unroll
    for (int i = 0; i < 8; ++i)
        outp[off + i] = (hv[i] - mu) * rs * gam[lane * 8 + i] + bet[lane * 8 + i];
}

extern "C" void kernel_launch(void* const* d_in, const int* in_sizes, int n_in,
                              void* d_out, int out_size, void* d_ws, size_t ws_size,
                              hipStream_t stream) {
    const float* x      = (const float*)d_in[0];
    const float* l_in_w = (const float*)d_in[1];
    const float* l_in_b = (const float*)d_in[2];
    const float* l_out_w= (const float*)d_in[3];
    const float* l_out_b= (const float*)d_in[4];
    const float* g_in_w = (const float*)d_in[5];
    const float* g_in_b = (const float*)d_in[6];
    const float* g_out_w= (const float*)d_in[7];
    const float* g_out_b= (const float*)d_in[8];
    const float* ffn_w1 = (const float*)d_in[9];
    const float* ffn_b1 = (const float*)d_in[10];
    const float* ffn_w2 = (const float*)d_in[11];
    const float* ffn_b2 = (const float*)d_in[12];
    const float* ln1_g  = (const float*)d_in[13];
    const float* ln1_b  = (const float*)d_in[14];
    const float* ln2_g  = (const float*)d_in[15];
    const float* ln2_b  = (const float*)d_in[16];

    char* ws = (char*)d_ws;
    // ---- workspace layout (peak 92.3 MB, liveness-checked) ----
    ushort* xb       = (ushort*)(ws + 0);          // 8.39 MB
    ushort* wb       = (ushort*)(ws + 8388608);    // 8.39 MB bf16 weights
    ushort* w_cat    = wb + 1572864;               // [512][1024] = [l_out_w | g_out_w]
    ushort* w1b      = wb + 2097152;
    ushort* w2b      = wb + 3145728;
    ushort* qkvb     = (ushort*)(ws + 16777216);   // 50.33 MB combined QKV [8192][3072]
    ushort* attnCat  = (ushort*)(ws + 67108864);   // 16.78 MB [8192][1024] (local|global)
    float*  projM    = (float*)(ws + 16777216);    // reuse qkvb (dead after attns)
    ushort* y1b      = (ushort*)(ws + 50331648);   // reuse qkvb tail
    float*  y1f      = (float*)(ws + 58720256);    // reuse qkvb tail (dead after projM)
    ushort* ffn1b    = (ushort*)(ws + 16777216);   // reuse projM (dead after ln1)
    float*  ffn2f    = (float*)(ws + 75497472);    // reuse attnCat upper (dead after projM)

    const int M = Bb * Ss;   // 8192

    cvt_all<<<dim3(8192), dim3(256), 0, stream>>>(x, l_in_w, g_in_w, l_out_w, g_out_w,
                                                  ffn_w1, ffn_w2, xb, wb);

    // merged QKV projection: C[8192][3072], dual bias
    gemm_bt<true, false><<<dim3(24, 64), 256, 0, stream>>>(
        xb, wb, l_in_b, g_in_b, 1536, qkvb, M, QS, Ee);

    // attention -> concatenated [8192][1024]
    attn_local_mfma<<<dim3(Bb * Hh * (Ss / 128)), 256, 0, stream>>>(qkvb, attnCat);
    attn_global_mfma<<<dim3(Bb * Hh * (Ss / 128)), 256, 0, stream>>>(qkvb + 1536, attnCat + 512);

    // merged output projection
    gemm64<true><<<dim3(Ee / 128, M / 64), 256, 0, stream>>>(
        attnCat, w_cat, l_out_b, g_out_b, projM, M, Ee, 1024);

    // residual + LN1
    ln_add2_dw<<<dim3(M / 4), 256, 0, stream>>>(x, projM, ln1_g, ln1_b, y1b, y1f);

    // FFN
    gemm_bt<true, true><<<dim3(16, 64), 256, 0, stream>>>(
        y1b, w1b, ffn_b1, ffn_b1, FFNd, ffn1b, M, FFNd, Ee);
    gemm64<false><<<dim3(Ee / 128, M / 64), 256, 0, stream>>>(
        ffn1b, w2b, ffn_b2, ffn_b2, ffn2f, M, Ee, FFNd);

    // residual + LN2 -> output
    ln_add2<<<dim3(M / 4), 256, 0, stream>>>(y1f, ffn2f, ln2_g, ln2_b, (float*)d_out);
}

// Round 12
// 288.806 us; speedup vs baseline: 15.0921x; 1.0225x over previous
//
#include <hip/hip_runtime.h>
#include <hip/hip_bf16.h>
#include <stdint.h>

#define Bb 8
#define Ss 1024
#define Ee 512
#define Hh 8
#define Dh 64
#define FFNd 2048
#define EPSv 1e-5f
#define QS 3072   // combined-QKV row stride (local 1536 | global 1536)
#define OS 1024   // concatenated attention-output row stride (local | global)

typedef float f32x4 __attribute__((ext_vector_type(4)));
typedef int   i32x4 __attribute__((ext_vector_type(4)));

__device__ inline float bf2f(ushort u) {
    uint32_t x = ((uint32_t)u) << 16; float f; __builtin_memcpy(&f, &x, 4); return f;
}
__device__ inline ushort f2bf(float f) {
    uint32_t x; __builtin_memcpy(&x, &f, 4);
    uint32_t r = (x + 0x7FFFu + ((x >> 16) & 1u)) >> 16; return (ushort)r;
}

// async global->LDS, 16B per lane; LDS dest = wave-uniform base + lane*16B
__device__ inline void gload16(const ushort* g, ushort* l) {
    __builtin_amdgcn_global_load_lds((const __attribute__((address_space(1))) void*)g,
                                     (__attribute__((address_space(3))) void*)l,
                                     16, 0, 0);
}

// V^T LDS swizzle (round-9 verified): V[kv][d] at Vtlds[(d*64+kv) ^ (((d&7)^((d>>3)&7))<<3)]
__device__ inline int vswz(int d, int kv) {
    return (d * 64 + kv) ^ ((((d & 7) ^ ((d >> 3) & 7)) & 7) << 3);
}

// ---- GEMM BK=64 LDS swizzle (T2 via pre-swizzled source, rule 21) ----
// Tile [R][64] bf16, linear gload_lds dest. Element (row, colblk j of 8) stored at
// elem offset row*64 + (j ^ (row&7))*8. Staging lane i (chunk of 8 rows): dest is
// linear lane*16B => row=i>>3, dest j=i&7 => source colblk = (i&7)^(i>>3).
// Read row=...+fr, j=kk*4+g => offset (row)*64 + ((kk*4+g)^(fr&7))*8.
// Read banks enumerate conflict-free (2 lanes/bank, free per m136).

// ---------------- fused fp32 -> bf16 conversion (x + all weights, 1 launch) ----------------
__device__ inline void cvt4_to(const float* src, int f, ushort* dst) {
    float4 v = *(const float4*)(src + f);
    ushort4 o;
    o.x = f2bf(v.x); o.y = f2bf(v.y); o.z = f2bf(v.z); o.w = f2bf(v.w);
    *(ushort4*)dst = o;
}
__global__ __launch_bounds__(256) void cvt_all(const float* __restrict__ s0, const float* __restrict__ s1,
                                               const float* __restrict__ s2, const float* __restrict__ s3,
                                               const float* __restrict__ s4, const float* __restrict__ s5,
                                               const float* __restrict__ s6,
                                               ushort* __restrict__ dx, ushort* __restrict__ dw) {
    int bid = blockIdx.x, tid = threadIdx.x;
    if (bid < 4096)      { int f = bid * 1024 + tid * 4;          cvt4_to(s0, f, dx + f); }
    else if (bid < 4864) { int f = (bid - 4096) * 1024 + tid * 4; cvt4_to(s1, f, dw + f); }
    else if (bid < 5632) { int f = (bid - 4864) * 1024 + tid * 4; cvt4_to(s2, f, dw + 786432 + f); }
    else if (bid < 5888) { int f = (bid - 5632) * 1024 + tid * 4; int n = f >> 9, k = f & 511;
                           cvt4_to(s3, f, dw + 1572864 + n * 1024 + k); }
    else if (bid < 6144) { int f = (bid - 5888) * 1024 + tid * 4; int n = f >> 9, k = f & 511;
                           cvt4_to(s4, f, dw + 1572864 + n * 1024 + 512 + k); }
    else if (bid < 7168) { int f = (bid - 6144) * 1024 + tid * 4; cvt4_to(s5, f, dw + 2097152 + f); }
    else                 { int f = (bid - 7168) * 1024 + tid * 4; cvt4_to(s6, f, dw + 3145728 + f); }
}

// ---------------- bf16 GEMM 128x128, BK=64, swizzled, single-buffered ----------------
template<bool OUT_BF16, bool RELU>
__global__ __launch_bounds__(256) void gemm_bt(const ushort* __restrict__ A,
                                               const ushort* __restrict__ Bm,
                                               const float* __restrict__ bias,
                                               const float* __restrict__ bias2, int nb1,
                                               void* __restrict__ C,
                                               int M, int N, int K) {
    __shared__ ushort Alds[128 * 64];
    __shared__ ushort Blds[128 * 64];
    int tid  = threadIdx.x;
    int lane = tid & 63, w = tid >> 6;
    int wr = w >> 1, wc = w & 1;
    int g  = lane >> 4, fr = lane & 15;
    int m0 = blockIdx.y * 128, n0 = blockIdx.x * 128;

    // staging: 16 chunks of 8 rows per matrix; wave w owns chunks 4w..4w+3
    int srow = lane >> 3;                  // row within chunk (== row&7)
    int sc8  = (lane & 7) ^ srow;          // pre-swizzled source col-block
    const ushort* gA = A  + (size_t)(m0 + w * 32 + srow) * K + sc8 * 8;
    const ushort* gB = Bm + (size_t)(n0 + w * 32 + srow) * K + sc8 * 8;
    ushort* lA = Alds + w * 2048;          // wave-uniform; HW adds lane*16B
    ushort* lB = Blds + w * 2048;

    f32x4 acc[4][4] = {};

    for (int kb = 0; kb < K; kb += 64) {
        __syncthreads();                   // prev iteration's LDS reads complete
        #pragma unroll
        for (int u = 0; u < 4; ++u) {
            gload16(gA + (size_t)u * 8 * K + kb, lA + u * 512);
            gload16(gB + (size_t)u * 8 * K + kb, lB + u * 512);
        }
        __syncthreads();                   // compiler drains vmcnt -> publish

        i32x4 af[4][2], bfr[4][2];
        #pragma unroll
        for (int mt = 0; mt < 4; ++mt)
            #pragma unroll
            for (int kk = 0; kk < 2; ++kk)
                af[mt][kk] = *(const i32x4*)(Alds + (wr * 64 + mt * 16 + fr) * 64
                                                  + (((kk * 4 + g) ^ (fr & 7)) * 8));
        #pragma unroll
        for (int nt = 0; nt < 4; ++nt)
            #pragma unroll
            for (int kk = 0; kk < 2; ++kk)
                bfr[nt][kk] = *(const i32x4*)(Blds + (wc * 64 + nt * 16 + fr) * 64
                                                   + (((kk * 4 + g) ^ (fr & 7)) * 8));
        #pragma unroll
        for (int kk = 0; kk < 2; ++kk)
            #pragma unroll
            for (int mt = 0; mt < 4; ++mt)
                #pragma unroll
                for (int nt = 0; nt < 4; ++nt)
                    asm("v_mfma_f32_16x16x32_bf16 %0, %1, %2, %0"
                        : "+v"(acc[mt][nt]) : "v"(af[mt][kk]), "v"(bfr[nt][kk]));
    }

    #pragma unroll
    for (int mt = 0; mt < 4; ++mt) {
        int r0 = m0 + wr * 64 + mt * 16 + g * 4;
        #pragma unroll
        for (int nt = 0; nt < 4; ++nt) {
            int c = n0 + wc * 64 + nt * 16 + fr;
            float bv = c < nb1 ? bias[c] : bias2[c - nb1];
            #pragma unroll
            for (int r = 0; r < 4; ++r) {
                float v = acc[mt][nt][r] + bv;
                if (RELU) v = v > 0.f ? v : 0.f;
                if (OUT_BF16) ((ushort*)C)[(size_t)(r0 + r) * N + c] = f2bf(v);
                else          ((float*)C)[(size_t)(r0 + r) * N + c] = v;
            }
        }
    }
}

// ---------------- bf16 GEMM 64x128, BK=64, swizzled (occupancy variant, f32 out) ----------------
template<bool SUMB>
__global__ __launch_bounds__(256) void gemm64(const ushort* __restrict__ A,
                                              const ushort* __restrict__ Bm,
                                              const float* __restrict__ bias,
                                              const float* __restrict__ bias2,
                                              float* __restrict__ C,
                                              int M, int N, int K) {
    __shared__ ushort Alds[64 * 64];
    __shared__ ushort Blds[128 * 64];
    int tid  = threadIdx.x;
    int lane = tid & 63, w = tid >> 6;
    int g  = lane >> 4, fr = lane & 15;
    int m0 = blockIdx.y * 64, n0 = blockIdx.x * 128;

    int srow = lane >> 3;
    int sc8  = (lane & 7) ^ srow;
    const ushort* gA = A  + (size_t)(m0 + w * 16 + srow) * K + sc8 * 8;   // 2 chunks/wave
    const ushort* gB = Bm + (size_t)(n0 + w * 32 + srow) * K + sc8 * 8;   // 4 chunks/wave
    ushort* lA = Alds + w * 1024;
    ushort* lB = Blds + w * 2048;

    f32x4 acc[4][2] = {};

    for (int kb = 0; kb < K; kb += 64) {
        __syncthreads();
        #pragma unroll
        for (int u = 0; u < 2; ++u)
            gload16(gA + (size_t)u * 8 * K + kb, lA + u * 512);
        #pragma unroll
        for (int u = 0; u < 4; ++u)
            gload16(gB + (size_t)u * 8 * K + kb, lB + u * 512);
        __syncthreads();

        i32x4 af[4][2], bfr[2][2];
        #pragma unroll
        for (int mt = 0; mt < 4; ++mt)
            #pragma unroll
            for (int kk = 0; kk < 2; ++kk)
                af[mt][kk] = *(const i32x4*)(Alds + (mt * 16 + fr) * 64
                                                  + (((kk * 4 + g) ^ (fr & 7)) * 8));
        #pragma unroll
        for (int nt = 0; nt < 2; ++nt)
            #pragma unroll
            for (int kk = 0; kk < 2; ++kk)
                bfr[nt][kk] = *(const i32x4*)(Blds + (w * 32 + nt * 16 + fr) * 64
                                                   + (((kk * 4 + g) ^ (fr & 7)) * 8));
        #pragma unroll
        for (int kk = 0; kk < 2; ++kk)
            #pragma unroll
            for (int mt = 0; mt < 4; ++mt)
                #pragma unroll
                for (int nt = 0; nt < 2; ++nt)
                    asm("v_mfma_f32_16x16x32_bf16 %0, %1, %2, %0"
                        : "+v"(acc[mt][nt]) : "v"(af[mt][kk]), "v"(bfr[nt][kk]));
    }

    #pragma unroll
    for (int mt = 0; mt < 4; ++mt) {
        int r0 = m0 + mt * 16 + g * 4;
        #pragma unroll
        for (int nt = 0; nt < 2; ++nt) {
            int c = n0 + w * 32 + nt * 16 + fr;
            float bv = SUMB ? bias[c] + bias2[c] : bias[c];
            #pragma unroll
            for (int r = 0; r < 4; ++r)
                C[(size_t)(r0 + r) * N + c] = acc[mt][nt][r] + bv;
        }
    }
}

// ---------------- global attention: MFMA flash, 128 q-rows/block, 4 waves ----------------
__global__ __launch_bounds__(256) void attn_global_mfma(const ushort* __restrict__ qkv,
                                                        ushort* __restrict__ out) {
    __shared__ ushort Klds[64 * 64];
    __shared__ ushort Vtlds[64 * 64];
    __shared__ ushort Plds[4][32 * 64];
    int tid  = threadIdx.x;
    int lane = tid & 63, w = tid >> 6;
    int fr = lane & 15, g = lane >> 4;
    int qtile = blockIdx.x & 7;
    int bh = blockIdx.x >> 3;
    int h = bh & 7, b = bh >> 3;
    const ushort* qp    = qkv + (size_t)b * Ss * QS + h * Dh;
    const ushort* kbase = qp + Ee;
    const ushort* vbase = qp + 2 * Ee;

    i32x4 qf[2][2];
    int q0 = qtile * 128 + w * 32;
    #pragma unroll
    for (int mt = 0; mt < 2; ++mt)
        #pragma unroll
        for (int kb = 0; kb < 2; ++kb)
            qf[mt][kb] = *(const i32x4*)(qp + (size_t)(q0 + mt * 16 + fr) * QS + kb * 32 + g * 8);

    f32x4 oacc[2][4] = {};
    f32x4 lsum[2] = {};
    ushort* Pw = Plds[w];

    i32x4 kr[2], vr[2];
    auto load_tile = [&](int kv0) {
        #pragma unroll
        for (int u = 0; u < 2; ++u) {
            int c = tid + u * 256;
            int row = c >> 3, col8 = c & 7;
            kr[u] = *(const i32x4*)(kbase + (size_t)(kv0 + row) * QS + col8 * 8);
            vr[u] = *(const i32x4*)(vbase + (size_t)(kv0 + row) * QS + col8 * 8);
        }
    };
    load_tile(0);

    for (int kt = 0; kt < 16; ++kt) {
        __syncthreads();
        #pragma unroll
        for (int u = 0; u < 2; ++u) {
            int c = tid + u * 256;
            int row = c >> 3, col8 = c & 7;
            int kidx = (row * 64 + col8 * 8) ^ ((row & 7) << 3);
            *(i32x4*)(Klds + kidx) = kr[u];
            ushort tmp[8];
            *(i32x4*)tmp = vr[u];
            #pragma unroll
            for (int j = 0; j < 8; ++j)
                Vtlds[vswz(col8 * 8 + j, row)] = tmp[j];
        }
        __syncthreads();
        if (kt < 15) load_tile((kt + 1) * 64);   // T14: next loads under compute

        f32x4 sacc[2][4] = {};
        i32x4 kf[4][2];
        #pragma unroll
        for (int nt = 0; nt < 4; ++nt) {
            int kvl = nt * 16 + fr;
            #pragma unroll
            for (int kb = 0; kb < 2; ++kb)
                kf[nt][kb] = *(const i32x4*)(Klds + ((kvl * 64 + kb * 32 + g * 8) ^ ((kvl & 7) << 3)));
        }
        #pragma unroll
        for (int mt = 0; mt < 2; ++mt)
            #pragma unroll
            for (int nt = 0; nt < 4; ++nt)
                #pragma unroll
                for (int kb = 0; kb < 2; ++kb)
                    asm("v_mfma_f32_16x16x32_bf16 %0, %1, %2, %0"
                        : "+v"(sacc[mt][nt]) : "v"(qf[mt][kb]), "v"(kf[nt][kb]));

        #pragma unroll
        for (int mt = 0; mt < 2; ++mt) {
            #pragma unroll
            for (int r = 0; r < 4; ++r) {
                int ql = mt * 16 + g * 4 + r;
                int sw = (ql & 7) << 3;
                float e0 = __expf(sacc[mt][0][r] * 0.125f);
                float e1 = __expf(sacc[mt][1][r] * 0.125f);
                float e2 = __expf(sacc[mt][2][r] * 0.125f);
                float e3 = __expf(sacc[mt][3][r] * 0.125f);
                Pw[(ql * 64 +  0 + fr) ^ sw] = f2bf(e0);
                Pw[(ql * 64 + 16 + fr) ^ sw] = f2bf(e1);
                Pw[(ql * 64 + 32 + fr) ^ sw] = f2bf(e2);
                Pw[(ql * 64 + 48 + fr) ^ sw] = f2bf(e3);
                lsum[mt][r] += (e0 + e1) + (e2 + e3);
            }
        }

        i32x4 pa[2][2], vf[4][2];
        #pragma unroll
        for (int mt = 0; mt < 2; ++mt) {
            int ql = mt * 16 + fr;
            #pragma unroll
            for (int kb = 0; kb < 2; ++kb)
                pa[mt][kb] = *(const i32x4*)(Pw + ((ql * 64 + kb * 32 + g * 8) ^ ((ql & 7) << 3)));
        }
        #pragma unroll
        for (int dn = 0; dn < 4; ++dn) {
            int d = dn * 16 + fr;
            #pragma unroll
            for (int kb = 0; kb < 2; ++kb)
                vf[dn][kb] = *(const i32x4*)(Vtlds + vswz(d, kb * 32 + g * 8));
        }
        #pragma unroll
        for (int mt = 0; mt < 2; ++mt)
            #pragma unroll
            for (int dn = 0; dn < 4; ++dn)
                #pragma unroll
                for (int kb = 0; kb < 2; ++kb)
                    asm("v_mfma_f32_16x16x32_bf16 %0, %1, %2, %0"
                        : "+v"(oacc[mt][dn]) : "v"(pa[mt][kb]), "v"(vf[dn][kb]));
    }

    #pragma unroll
    for (int mt = 0; mt < 2; ++mt)
        #pragma unroll
        for (int r = 0; r < 4; ++r) {
            float s = lsum[mt][r];
            s += __shfl_xor(s, 1); s += __shfl_xor(s, 2);
            s += __shfl_xor(s, 4); s += __shfl_xor(s, 8);
            lsum[mt][r] = 1.f / s;
        }

    #pragma unroll
    for (int mt = 0; mt < 2; ++mt)
        #pragma unroll
        for (int r = 0; r < 4; ++r) {
            int qg = q0 + mt * 16 + g * 4 + r;
            size_t ob = (size_t)(b * Ss + qg) * OS + h * Dh;
            #pragma unroll
            for (int dn = 0; dn < 4; ++dn)
                out[ob + dn * 16 + fr] = f2bf(oacc[mt][dn][r] * lsum[mt][r]);
        }
}

// ---------------- local windowed attention: MFMA flash over the band tiles ----------------
__global__ __launch_bounds__(256) void attn_local_mfma(const ushort* __restrict__ qkv,
                                                       ushort* __restrict__ out) {
    __shared__ ushort Klds[64 * 64];
    __shared__ ushort Vtlds[64 * 64];
    __shared__ ushort Plds[4][32 * 64];
    int tid  = threadIdx.x;
    int lane = tid & 63, w = tid >> 6;
    int fr = lane & 15, g = lane >> 4;
    int qtile = blockIdx.x & 7;
    int bh = blockIdx.x >> 3;
    int h = bh & 7, b = bh >> 3;
    const ushort* qp    = qkv + (size_t)b * Ss * QS + h * Dh;
    const ushort* kbase = qp + Ee;
    const ushort* vbase = qp + 2 * Ee;

    i32x4 qf[2][2];
    int q0 = qtile * 128 + w * 32;
    #pragma unroll
    for (int mt = 0; mt < 2; ++mt)
        #pragma unroll
        for (int kb = 0; kb < 2; ++kb)
            qf[mt][kb] = *(const i32x4*)(qp + (size_t)(q0 + mt * 16 + fr) * QS + kb * 32 + g * 8);

    f32x4 oacc[2][4] = {};
    f32x4 lsum[2] = {};
    ushort* Pw = Plds[w];

    i32x4 kr[2], vr[2];
    auto load_tile = [&](int kv0) {
        #pragma unroll
        for (int u = 0; u < 2; ++u) {
            int c = tid + u * 256;
            int row = c >> 3, col8 = c & 7;
            kr[u] = *(const i32x4*)(kbase + (size_t)(kv0 + row) * QS + col8 * 8);
            vr[u] = *(const i32x4*)(vbase + (size_t)(kv0 + row) * QS + col8 * 8);
        }
    };

    int tq2 = qtile * 2;
    int kt0 = tq2 > 0 ? tq2 - 1 : 0;
    int kt1 = tq2 + 2 < 16 ? tq2 + 2 : 15;
    load_tile(kt0 * 64);

    for (int kt = kt0; kt <= kt1; ++kt) {
        int kv0 = kt * 64;
        __syncthreads();
        #pragma unroll
        for (int u = 0; u < 2; ++u) {
            int c = tid + u * 256;
            int row = c >> 3, col8 = c & 7;
            int kidx = (row * 64 + col8 * 8) ^ ((row & 7) << 3);
            *(i32x4*)(Klds + kidx) = kr[u];
            ushort tmp[8];
            *(i32x4*)tmp = vr[u];
            #pragma unroll
            for (int j = 0; j < 8; ++j)
                Vtlds[vswz(col8 * 8 + j, row)] = tmp[j];
        }
        __syncthreads();
        if (kt < kt1) load_tile((kt + 1) * 64);

        bool active = (kv0 <= q0 + 36) && (kv0 + 63 >= q0 - 5);
        if (active) {
            f32x4 sacc[2][4] = {};
            i32x4 kf[4][2];
            #pragma unroll
            for (int nt = 0; nt < 4; ++nt) {
                int kvl = nt * 16 + fr;
                #pragma unroll
                for (int kb = 0; kb < 2; ++kb)
                    kf[nt][kb] = *(const i32x4*)(Klds + ((kvl * 64 + kb * 32 + g * 8) ^ ((kvl & 7) << 3)));
            }
            #pragma unroll
            for (int mt = 0; mt < 2; ++mt)
                #pragma unroll
                for (int nt = 0; nt < 4; ++nt)
                    #pragma unroll
                    for (int kb = 0; kb < 2; ++kb)
                        asm("v_mfma_f32_16x16x32_bf16 %0, %1, %2, %0"
                            : "+v"(sacc[mt][nt]) : "v"(qf[mt][kb]), "v"(kf[nt][kb]));

            #pragma unroll
            for (int mt = 0; mt < 2; ++mt) {
                #pragma unroll
                for (int r = 0; r < 4; ++r) {
                    int ql = mt * 16 + g * 4 + r;
                    int sw = (ql & 7) << 3;
                    int d0 = (q0 + ql) - (kv0 + fr);
                    int d1 = d0 - 16, d2 = d0 - 32, d3 = d0 - 48;
                    float e0 = (d0 >= -5 && d0 <= 5) ? __expf(sacc[mt][0][r] * 0.125f) : 0.f;
                    float e1 = (d1 >= -5 && d1 <= 5) ? __expf(sacc[mt][1][r] * 0.125f) : 0.f;
                    float e2 = (d2 >= -5 && d2 <= 5) ? __expf(sacc[mt][2][r] * 0.125f) : 0.f;
                    float e3 = (d3 >= -5 && d3 <= 5) ? __expf(sacc[mt][3][r] * 0.125f) : 0.f;
                    Pw[(ql * 64 +  0 + fr) ^ sw] = f2bf(e0);
                    Pw[(ql * 64 + 16 + fr) ^ sw] = f2bf(e1);
                    Pw[(ql * 64 + 32 + fr) ^ sw] = f2bf(e2);
                    Pw[(ql * 64 + 48 + fr) ^ sw] = f2bf(e3);
                    lsum[mt][r] += (e0 + e1) + (e2 + e3);
                }
            }

            i32x4 pa[2][2], vf[4][2];
            #pragma unroll
            for (int mt = 0; mt < 2; ++mt) {
                int ql = mt * 16 + fr;
                #pragma unroll
                for (int kb = 0; kb < 2; ++kb)
                    pa[mt][kb] = *(const i32x4*)(Pw + ((ql * 64 + kb * 32 + g * 8) ^ ((ql & 7) << 3)));
            }
            #pragma unroll
            for (int dn = 0; dn < 4; ++dn) {
                int d = dn * 16 + fr;
                #pragma unroll
                for (int kb = 0; kb < 2; ++kb)
                    vf[dn][kb] = *(const i32x4*)(Vtlds + vswz(d, kb * 32 + g * 8));
            }
            #pragma unroll
            for (int mt = 0; mt < 2; ++mt)
                #pragma unroll
                for (int dn = 0; dn < 4; ++dn)
                    #pragma unroll
                    for (int kb = 0; kb < 2; ++kb)
                        asm("v_mfma_f32_16x16x32_bf16 %0, %1, %2, %0"
                            : "+v"(oacc[mt][dn]) : "v"(pa[mt][kb]), "v"(vf[dn][kb]));
        }
    }

    #pragma unroll
    for (int mt = 0; mt < 2; ++mt)
        #pragma unroll
        for (int r = 0; r < 4; ++r) {
            float s = lsum[mt][r];
            s += __shfl_xor(s, 1); s += __shfl_xor(s, 2);
            s += __shfl_xor(s, 4); s += __shfl_xor(s, 8);
            lsum[mt][r] = 1.f / s;
        }

    #pragma unroll
    for (int mt = 0; mt < 2; ++mt)
        #pragma unroll
        for (int r = 0; r < 4; ++r) {
            int qg = q0 + mt * 16 + g * 4 + r;
            size_t ob = (size_t)(b * Ss + qg) * OS + h * Dh;
            #pragma unroll
            for (int dn = 0; dn < 4; ++dn)
                out[ob + dn * 16 + fr] = f2bf(oacc[mt][dn][r] * lsum[mt][r]);
        }
}

// ---------------- fused residual(2-way) + LayerNorm, dual write (bf16 + f32) ----------------
__global__ __launch_bounds__(256) void ln_add2_dw(const float* __restrict__ x,
                                                  const float* __restrict__ p1,
                                                  const float* __restrict__ gam,
                                                  const float* __restrict__ bet,
                                                  ushort* __restrict__ yb,
                                                  float* __restrict__ yf) {
    int row  = blockIdx.x * 4 + (threadIdx.x >> 6);
    int lane = threadIdx.x & 63;
    size_t off = (size_t)row * Ee + lane * 8;
    float hv[8];
    float4 a0 = *(const float4*)(x + off),  a1 = *(const float4*)(x + off + 4);
    float4 b0 = *(const float4*)(p1 + off), b1 = *(const float4*)(p1 + off + 4);
    hv[0] = a0.x + b0.x; hv[1] = a0.y + b0.y; hv[2] = a0.z + b0.z; hv[3] = a0.w + b0.w;
    hv[4] = a1.x + b1.x; hv[5] = a1.y + b1.y; hv[6] = a1.z + b1.z; hv[7] = a1.w + b1.w;
    float s = 0.f;
    #pragma unroll
    for (int i = 0; i < 8; ++i) s += hv[i];
    #pragma unroll
    for (int o = 32; o; o >>= 1) s += __shfl_xor(s, o);
    float mu = s * (1.f / Ee);
    float vs = 0.f;
    #pragma unroll
    for (int i = 0; i < 8; ++i) { float d = hv[i] - mu; vs += d * d; }
    #pragma unroll
    for (int o = 32; o; o >>= 1) vs += __shfl_xor(vs, o);
    float rs = rsqrtf(vs * (1.f / Ee) + EPSv);
    #pragma unroll
    for (int i = 0; i < 8; ++i) {
        float yv = (hv[i] - mu) * rs * gam[lane * 8 + i] + bet[lane * 8 + i];
        yf[off + i] = yv;
        yb[off + i] = f2bf(yv);
    }
}

// ---------------- fused residual(2-way) + LayerNorm -> f32 out ----------------
__global__ __launch_bounds__(256) void ln_add2(const float* __restrict__ a,
                                               const float* __restrict__ bsrc,
                                               const float* __restrict__ gam,
                                               const float* __restrict__ bet,
                                               float* __restrict__ outp) {
    int row  = blockIdx.x * 4 + (threadIdx.x >> 6);
    int lane = threadIdx.x & 63;
    size_t off = (size_t)row * Ee + lane * 8;
    float hv[8];
    float4 a0 = *(const float4*)(a + off),    a1 = *(const float4*)(a + off + 4);
    float4 b0 = *(const float4*)(bsrc + off), b1 = *(const float4*)(bsrc + off + 4);
    hv[0] = a0.x + b0.x; hv[1] = a0.y + b0.y; hv[2] = a0.z + b0.z; hv[3] = a0.w + b0.w;
    hv[4] = a1.x + b1.x; hv[5] = a1.y + b1.y; hv[6] = a1.z + b1.z; hv[7] = a1.w + b1.w;
    float s = 0.f;
    #pragma unroll
    for (int i = 0; i < 8; ++i) s += hv[i];
    #pragma unroll
    for (int o = 32; o; o >>= 1) s += __shfl_xor(s, o);
    float mu = s * (1.f / Ee);
    float vs = 0.f;
    #pragma unroll
    for (int i = 0; i < 8; ++i) { float d = hv[i] - mu; vs += d * d; }
    #pragma unroll
    for (int o = 32; o; o >>= 1) vs += __shfl_xor(vs, o);
    float rs = rsqrtf(vs * (1.f / Ee) + EPSv);
    #pragma unroll
    for (int i = 0; i < 8; ++i)
        outp[off + i] = (hv[i] - mu) * rs * gam[lane * 8 + i] + bet[lane * 8 + i];
}

extern "C" void kernel_launch(void* const* d_in, const int* in_sizes, int n_in,
                              void* d_out, int out_size, void* d_ws, size_t ws_size,
                              hipStream_t stream) {
    const float* x      = (const float*)d_in[0];
    const float* l_in_w = (const float*)d_in[1];
    const float* l_in_b = (const float*)d_in[2];
    const float* l_out_w= (const float*)d_in[3];
    const float* l_out_b= (const float*)d_in[4];
    const float* g_in_w = (const float*)d_in[5];
    const float* g_in_b = (const float*)d_in[6];
    const float* g_out_w= (const float*)d_in[7];
    const float* g_out_b= (const float*)d_in[8];
    const float* ffn_w1 = (const float*)d_in[9];
    const float* ffn_b1 = (const float*)d_in[10];
    const float* ffn_w2 = (const float*)d_in[11];
    const float* ffn_b2 = (const float*)d_in[12];
    const float* ln1_g  = (const float*)d_in[13];
    const float* ln1_b  = (const float*)d_in[14];
    const float* ln2_g  = (const float*)d_in[15];
    const float* ln2_b  = (const float*)d_in[16];

    char* ws = (char*)d_ws;
    // ---- workspace layout (peak 92.3 MB, liveness-checked) ----
    ushort* xb       = (ushort*)(ws + 0);          // 8.39 MB
    ushort* wb       = (ushort*)(ws + 8388608);    // 8.39 MB bf16 weights
    ushort* w_cat    = wb + 1572864;               // [512][1024] = [l_out_w | g_out_w]
    ushort* w1b      = wb + 2097152;
    ushort* w2b      = wb + 3145728;
    ushort* qkvb     = (ushort*)(ws + 16777216);   // 50.33 MB combined QKV [8192][3072]
    ushort* attnCat  = (ushort*)(ws + 67108864);   // 16.78 MB [8192][1024] (local|global)
    float*  projM    = (float*)(ws + 16777216);    // reuse qkvb (dead after attns)
    ushort* y1b      = (ushort*)(ws + 50331648);   // reuse qkvb tail
    float*  y1f      = (float*)(ws + 58720256);    // reuse qkvb tail (dead after projM)
    ushort* ffn1b    = (ushort*)(ws + 16777216);   // reuse projM (dead after ln1)
    float*  ffn2f    = (float*)(ws + 75497472);    // reuse attnCat upper (dead after projM)

    const int M = Bb * Ss;   // 8192

    cvt_all<<<dim3(8192), dim3(256), 0, stream>>>(x, l_in_w, g_in_w, l_out_w, g_out_w,
                                                  ffn_w1, ffn_w2, xb, wb);

    // merged QKV projection: C[8192][3072], dual bias
    gemm_bt<true, false><<<dim3(24, 64), 256, 0, stream>>>(
        xb, wb, l_in_b, g_in_b, 1536, qkvb, M, QS, Ee);

    // attention -> concatenated [8192][1024]
    attn_local_mfma<<<dim3(Bb * Hh * (Ss / 128)), 256, 0, stream>>>(qkvb, attnCat);
    attn_global_mfma<<<dim3(Bb * Hh * (Ss / 128)), 256, 0, stream>>>(qkvb + 1536, attnCat + 512);

    // merged output projection
    gemm64<true><<<dim3(Ee / 128, M / 64), 256, 0, stream>>>(
        attnCat, w_cat, l_out_b, g_out_b, projM, M, Ee, 1024);

    // residual + LN1
    ln_add2_dw<<<dim3(M / 4), 256, 0, stream>>>(x, projM, ln1_g, ln1_b, y1b, y1f);

    // FFN
    gemm_bt<true, true><<<dim3(16, 64), 256, 0, stream>>>(
        y1b, w1b, ffn_b1, ffn_b1, FFNd, ffn1b, M, FFNd, Ee);
    gemm64<false><<<dim3(Ee / 128, M / 64), 256, 0, stream>>>(
        ffn1b, w2b, ffn_b2, ffn_b2, ffn2f, M, Ee, FFNd);

    // residual + LN2 -> output
    ln_add2<<<dim3(M / 4), 256, 0, stream>>>(y1f, ffn2f, ln2_g, ln2_b, (float*)d_out);
}